// Round 8
// baseline (965.877 us; speedup 1.0000x reference)
//
#include <hip/hip_runtime.h>
#include <hip/hip_bf16.h>
#include <math.h>

constexpr int N    = 50000;
constexpr int NE   = 500000;
constexpr int IN   = 128;
constexpr int H    = 8;
constexpr int D    = 16;
constexpr int DSEM = 4;
constexpr int KS   = 21;
constexpr float CLAMP = 5.0f;

typedef __attribute__((ext_vector_type(8))) __bf16 bf16x8;
typedef __attribute__((ext_vector_type(4))) float  f32x4;

__device__ inline f32x4 mfma16(bf16x8 a, bf16x8 b, f32x4 c) {
    return __builtin_amdgcn_mfma_f32_16x16x32_bf16(a, b, c, 0, 0, 0);
}

__device__ inline void split_bf16(float f, unsigned& hi, unsigned& lo) {
    unsigned u = __float_as_uint(f);
    hi = (u + 0x7FFFu + ((u >> 16) & 1u)) >> 16;
    float fl = f - __uint_as_float(hi << 16);
    unsigned ul = __float_as_uint(fl);
    lo = (ul + 0x7FFFu + ((ul >> 16) & 1u)) >> 16;
}

__device__ inline void split2(float a, float b, unsigned& hi, unsigned& lo) {
    unsigned ha, la, hb, lb;
    split_bf16(a, ha, la);
    split_bf16(b, hb, lb);
    hi = ha | (hb << 16);
    lo = la | (lb << 16);
}

__device__ inline ushort f2bf(float f) {
    unsigned u = __float_as_uint(f);
    return (ushort)((u + 0x7FFFu + ((u >> 16) & 1u)) >> 16);
}
__device__ inline float bf2f(ushort u) {
    return __uint_as_float(((unsigned)u) << 16);
}

// ---------------------------------------------------------------------------
// prep_w: split [Ew (256 rows); wew (8 rows); zeros (8 rows)] = 272x128 into
// bf16 hi/lo, fragment-linear.  17 o-tiles.
// ---------------------------------------------------------------------------
__global__ __launch_bounds__(256) void prep_w_kernel(
    const float* __restrict__ Ew, const float* __restrict__ wew,
    ushort* __restrict__ EwHiF, ushort* __restrict__ EwLoF)
{
    int tid = blockIdx.x * 256 + threadIdx.x;          // 0..4351
    int l  = tid & 63;
    int ks = (tid >> 6) & 3;
    int ot = tid >> 8;                                 // 0..16
    int row = 16 * ot + (l & 15);
    int col = 32 * ks + 8 * (l >> 4);
    float4 f0, f1;
    if (row < 256) {
        const float* src = Ew + (size_t)row * 128 + col;
        f0 = *(const float4*)(src);
        f1 = *(const float4*)(src + 4);
    } else if (row < 264) {
        const float* src = wew + (size_t)(row - 256) * 128 + col;
        f0 = *(const float4*)(src);
        f1 = *(const float4*)(src + 4);
    } else {
        f0 = f1 = make_float4(0.f, 0.f, 0.f, 0.f);
    }
    unsigned H0,L0,H1,L1,H2,L2,H3,L3;
    split2(f0.x, f0.y, H0, L0);
    split2(f0.z, f0.w, H1, L1);
    split2(f1.x, f1.y, H2, L2);
    split2(f1.z, f1.w, H3, L3);
    *(uint4*)(EwHiF + (size_t)tid * 8) = make_uint4(H0, H1, H2, H3);
    *(uint4*)(EwLoF + (size_t)tid * 8) = make_uint4(L0, L1, L2, L3);
}

// ---------------------------------------------------------------------------
// prep_qkvw: split concat(Qw,Kw,Vw) (384x128) into bf16 hi/lo, frag-linear.
// ---------------------------------------------------------------------------
__global__ __launch_bounds__(256) void prep_qkvw_kernel(
    const float* __restrict__ Qw, const float* __restrict__ Kw,
    const float* __restrict__ Vw,
    ushort* __restrict__ WHiF, ushort* __restrict__ WLoF)
{
    int tid = blockIdx.x * 256 + threadIdx.x;          // 0..6143
    int l  = tid & 63;
    int ks = (tid >> 6) & 3;
    int ot = tid >> 8;                                 // 0..23
    int row = 16 * ot + (l & 15);                      // 0..383
    int col = 32 * ks + 8 * (l >> 4);
    const float* wrow = (row < 128) ? (Qw + (size_t)row * 128)
                      : (row < 256) ? (Kw + (size_t)(row - 128) * 128)
                                    : (Vw + (size_t)(row - 256) * 128);
    const float* src = wrow + col;
    float4 f0 = *(const float4*)(src);
    float4 f1 = *(const float4*)(src + 4);
    unsigned H0,L0,H1,L1,H2,L2,H3,L3;
    split2(f0.x, f0.y, H0, L0);
    split2(f0.z, f0.w, H1, L1);
    split2(f1.x, f1.y, H2, L2);
    split2(f1.z, f1.w, H3, L3);
    *(uint4*)(WHiF + (size_t)tid * 8) = make_uint4(H0, H1, H2, H3);
    *(uint4*)(WLoF + (size_t)tid * 8) = make_uint4(L0, L1, L2, L3);
}

// ---------------------------------------------------------------------------
// K1: QKV split-bf16 MFMA + RoPE.  32 nodes/block, W direct global->reg.
// (unchanged from round 7)
// ---------------------------------------------------------------------------
constexpr int QNPB   = 32;
constexpr int QA_HI  = 0;
constexpr int QA_LO  = 8192;
constexpr int QSO_S  = 388;
constexpr int QSRR_OFF = 49664;
constexpr int QSC_OFF  = 52736;
constexpr int QSS_OFF  = 58880;
constexpr int Q_LDS    = 65024;

__global__ __launch_bounds__(256, 2) void qkv_mfma_kernel(
    const float* __restrict__ x, const float* __restrict__ rrwp,
    const ushort* __restrict__ WHiF, const ushort* __restrict__ WLoF,
    const float* __restrict__ Qb, const float* __restrict__ Kb,
    const float* __restrict__ Vb, const float* __restrict__ Wang,
    float* __restrict__ Qh, float* __restrict__ Kh, float* __restrict__ Vh)
{
    __shared__ __align__(16) char smem[Q_LDS];

    const int t    = threadIdx.x;
    const int wid  = t >> 6;
    const int lane = t & 63;
    const int nb0  = blockIdx.x * QNPB;

    float* srr = (float*)(smem + QSRR_OFF);
    float* scc = (float*)(smem + QSC_OFF);
    float* sss = (float*)(smem + QSS_OFF);

    for (int i = t; i < QNPB * KS; i += 256) {
        int nl = i / KS, k = i % KS;
        int n = nb0 + nl;
        srr[nl * 24 + k] = (n < N) ? rrwp[(size_t)n * KS + k] : 0.0f;
    }

    {
        const int se = t >> 3, sq = t & 7;
        const int sn = nb0 + se;
        const int g = se >> 4, sr = se & 15;
        const int cs2 = sq >> 1, lb = 2 * (sq & 1);
        const int abase = ((g * 4 + cs2) * 64 + lb * 16 + sr) * 16;
        float4 v0, v1, v2, v3;
        if (sn < N) {
            const float4* ar = (const float4*)(x + (size_t)sn * 128 + sq * 16);
            v0 = ar[0]; v1 = ar[1]; v2 = ar[2]; v3 = ar[3];
        } else {
            v0 = v1 = v2 = v3 = make_float4(0.f, 0.f, 0.f, 0.f);
        }
        unsigned H0,L0,H1,L1,H2,L2,H3,L3,H4,L4,H5,L5,H6,L6,H7,L7;
        split2(v0.x, v0.y, H0, L0); split2(v0.z, v0.w, H1, L1);
        split2(v1.x, v1.y, H2, L2); split2(v1.z, v1.w, H3, L3);
        split2(v2.x, v2.y, H4, L4); split2(v2.z, v2.w, H5, L5);
        split2(v3.x, v3.y, H6, L6); split2(v3.z, v3.w, H7, L7);
        *(uint4*)(smem + QA_HI + abase)       = make_uint4(H0, H1, H2, H3);
        *(uint4*)(smem + QA_HI + abase + 256) = make_uint4(H4, H5, H6, H7);
        *(uint4*)(smem + QA_LO + abase)       = make_uint4(L0, L1, L2, L3);
        *(uint4*)(smem + QA_LO + abase + 256) = make_uint4(L4, L5, L6, L7);
    }
    __syncthreads();

    f32x4 acc[2][6];
    #pragma unroll
    for (int g = 0; g < 2; g++)
        #pragma unroll
        for (int o = 0; o < 6; o++)
            acc[g][o] = (f32x4){0.f, 0.f, 0.f, 0.f};

    #pragma unroll
    for (int cs2 = 0; cs2 < 4; cs2++) {
        bf16x8 Ah[2], Al[2];
        #pragma unroll
        for (int g = 0; g < 2; g++) {
            int off = ((g * 4 + cs2) * 64 + lane) * 16;
            Ah[g] = *(const bf16x8*)(smem + QA_HI + off);
            Al[g] = *(const bf16x8*)(smem + QA_LO + off);
        }
        #pragma unroll
        for (int otl = 0; otl < 6; otl++) {
            int ot = wid * 6 + otl;
            size_t woff = (size_t)((ot * 4 + cs2) * 64 + lane) * 16;
            bf16x8 Bh = *(const bf16x8*)((const char*)WHiF + woff);
            bf16x8 Bl = *(const bf16x8*)((const char*)WLoF + woff);
            #pragma unroll
            for (int g = 0; g < 2; g++) {
                acc[g][otl] = mfma16(Ah[g], Bh, acc[g][otl]);
                acc[g][otl] = mfma16(Al[g], Bh, acc[g][otl]);
                acc[g][otl] = mfma16(Ah[g], Bl, acc[g][otl]);
            }
        }
    }
    __syncthreads();

    float* sout = (float*)smem;
    const int lr4 = (lane >> 4) * 4;
    const int lc  = lane & 15;
    #pragma unroll
    for (int otl = 0; otl < 6; otl++) {
        int o = (wid * 6 + otl) * 16 + lc;
        float bv = (o < 128) ? Qb[o] : (o < 256) ? Kb[o - 128] : Vb[o - 256];
        #pragma unroll
        for (int g = 0; g < 2; g++) {
            int e = 16 * g + lr4;
            #pragma unroll
            for (int jr = 0; jr < 4; jr++)
                sout[(e + jr) * QSO_S + o] = acc[g][otl][jr] + bv;
        }
    }
    __syncthreads();

    for (int i = t; i < QNPB * 48; i += 256) {
        int nl = i / 48, a = i % 48;
        int h = a / 6, r = a % 6;
        float av = 0.0f;
        #pragma unroll
        for (int k = 0; k < KS; k++)
            av = fmaf(srr[nl * 24 + k], Wang[(size_t)(h * KS + k) * 6 + r], av);
        float sv, cv;
        sincosf(av, &sv, &cv);
        scc[nl * 48 + a] = cv;
        sss[nl * 48 + a] = sv;
    }
    __syncthreads();

    for (int i = t; i < QNPB * 384; i += 256) {
        int nl = i / 384, o = i % 384;
        int n = nb0 + nl;
        if (n >= N) continue;
        int mat = o >> 7;
        int oo  = o & 127;
        int h = oo >> 4, d = oo & 15;
        float val;
        if (mat == 2 || d < DSEM) {
            val = sout[nl * QSO_S + o];
        } else {
            int i2 = (d - DSEM) >> 1;
            float cv = scc[nl * 48 + h * 6 + i2];
            float sv = sss[nl * 48 + h * 6 + i2];
            int base = (mat << 7) + h * 16 + DSEM + 2 * i2;
            float xe = sout[nl * QSO_S + base];
            float xo = sout[nl * QSO_S + base + 1];
            val = ((d & 1) == 0) ? (xe * cv - xo * sv) : (xe * sv + xo * cv);
        }
        float* dp = (mat == 0) ? Qh : (mat == 1) ? Kh : Vh;
        dp[(size_t)n * 128 + oo] = val;
    }
}

// ---------------------------------------------------------------------------
// K2 v4: split-bf16 MFMA edge GEMM.
//  - launch_bounds(256,3): VGPR cap 170 (no spills), 3 blocks/CU @ 39.9 KB
//  - BOTH K-chunks staged up-front (A = [4g][4ks2][64][16B] hi+lo = 32 KB,
//    overlapped by the 36.9 KB bf16 sOut after the GEMM barrier)
//  - single barrier-free MFMA loop over 4 k-slices
//  - non-temporal wE stores (no write-allocate on 256 MB output)
// ---------------------------------------------------------------------------
constexpr int AHI_OFF = 0;        // [4 g][4 ks2g][64 l][16 B] = 16384
constexpr int ALO_OFF = 16384;    // ends 32768
constexpr int SOB_S   = 288;      // ushorts per edge row (8 heads x 36)
constexpr int SOB_H   = 36;
constexpr int SBIAS_OFF = 64 * SOB_S * 2;             // 36864
constexpr int EDG_LDS   = SBIAS_OFF + 64 * 12 * 4;    // 39936

__global__ __launch_bounds__(256, 3) void edge_gemm_kernel(
    const float* __restrict__ edge_attr,
    const int* __restrict__ srcI, const int* __restrict__ dstI,
    const float* __restrict__ Qh, const float* __restrict__ Kh,
    const ushort* __restrict__ EwHiF, const ushort* __restrict__ EwLoF,
    const float* __restrict__ Eb, const float* __restrict__ web,
    float* __restrict__ wE, float* __restrict__ exOut)
{
    __shared__ __align__(16) char smem[EDG_LDS];

    const int t    = threadIdx.x;
    const int wid  = t >> 6;
    const int lane = t & 63;
    const int eb0  = blockIdx.x * 64;

    const int se   = t >> 2;
    const int sq   = t & 3;
    const int sge  = eb0 + se;
    const int sr   = se & 15;
    const int sg   = se >> 4;
    const int sks2 = sq >> 1;
    const int slb  = 2 * (sq & 1);

    // ---- stage BOTH chunks up-front ----
    #pragma unroll
    for (int c = 0; c < 2; c++) {
        float4 v0, v1, v2, v3;
        if (sge < NE) {
            const float4* ar = (const float4*)(edge_attr + (size_t)sge * 128 + c * 64 + sq * 16);
            v0 = ar[0]; v1 = ar[1]; v2 = ar[2]; v3 = ar[3];
        } else {
            v0 = v1 = v2 = v3 = make_float4(0.f, 0.f, 0.f, 0.f);
        }
        unsigned H0,L0,H1,L1,H2,L2,H3,L3,H4,L4,H5,L5,H6,L6,H7,L7;
        split2(v0.x, v0.y, H0, L0); split2(v0.z, v0.w, H1, L1);
        split2(v1.x, v1.y, H2, L2); split2(v1.z, v1.w, H3, L3);
        split2(v2.x, v2.y, H4, L4); split2(v2.z, v2.w, H5, L5);
        split2(v3.x, v3.y, H6, L6); split2(v3.z, v3.w, H7, L7);
        const int abase = ((sg * 4 + c * 2 + sks2) * 64 + slb * 16 + sr) * 16;
        *(uint4*)(smem + AHI_OFF + abase)       = make_uint4(H0, H1, H2, H3);
        *(uint4*)(smem + AHI_OFF + abase + 256) = make_uint4(H4, H5, H6, H7);
        *(uint4*)(smem + ALO_OFF + abase)       = make_uint4(L0, L1, L2, L3);
        *(uint4*)(smem + ALO_OFF + abase + 256) = make_uint4(L4, L5, L6, L7);
    }

    const int e_l = se;
    const int geC = (sge < NE) ? sge : (NE - 1);
    const int sIdx = srcI[geC];
    const int dIdx = dstI[geC];

    f32x4 acc[4][4];
    #pragma unroll
    for (int g = 0; g < 4; g++)
        #pragma unroll
        for (int o = 0; o < 4; o++)
            acc[g][o] = (f32x4){0.f, 0.f, 0.f, 0.f};
    f32x4 accb[4];
    #pragma unroll
    for (int g = 0; g < 4; g++) accb[g] = (f32x4){0.f, 0.f, 0.f, 0.f};

    __syncthreads();

    // ---- single MFMA loop over 4 k-slices, no barriers ----
    #pragma unroll
    for (int ks2g = 0; ks2g < 4; ks2g++) {
        bf16x8 Wh[4], Wl[4];
        #pragma unroll
        for (int otl = 0; otl < 4; otl++) {
            int ot = wid * 4 + otl;
            size_t woff = (size_t)((ot * 4 + ks2g) * 64 + lane) * 16;
            Wh[otl] = *(const bf16x8*)((const char*)EwHiF + woff);
            Wl[otl] = *(const bf16x8*)((const char*)EwLoF + woff);
        }
        bf16x8 Bbh, Bbl;
        if (wid == 0) {
            size_t woff = (size_t)((16 * 4 + ks2g) * 64 + lane) * 16;
            Bbh = *(const bf16x8*)((const char*)EwHiF + woff);
            Bbl = *(const bf16x8*)((const char*)EwLoF + woff);
        }
        bf16x8 Ah[4], Al[4];
        #pragma unroll
        for (int g = 0; g < 4; g++) {
            int off = ((g * 4 + ks2g) * 64 + lane) * 16;
            Ah[g] = *(const bf16x8*)(smem + AHI_OFF + off);
            Al[g] = *(const bf16x8*)(smem + ALO_OFF + off);
        }
        #pragma unroll
        for (int otl = 0; otl < 4; otl++) {
            #pragma unroll
            for (int g = 0; g < 4; g++) {
                acc[g][otl] = mfma16(Ah[g], Wh[otl], acc[g][otl]);
                acc[g][otl] = mfma16(Al[g], Wh[otl], acc[g][otl]);
                acc[g][otl] = mfma16(Ah[g], Wl[otl], acc[g][otl]);
            }
        }
        if (wid == 0) {
            #pragma unroll
            for (int g = 0; g < 4; g++) {
                accb[g] = mfma16(Ah[g], Bbh, accb[g]);
                accb[g] = mfma16(Al[g], Bbh, accb[g]);
                accb[g] = mfma16(Ah[g], Bbl, accb[g]);
            }
        }
    }
    __syncthreads();

    // ---- acc -> bf16 sOut (+Eb), accb -> sBias (+web) ----
    ushort* sOutB = (ushort*)smem;
    float*  sBias = (float*)(smem + SBIAS_OFF);
    const int lr4 = (lane >> 4) * 4;
    const int lc  = lane & 15;
    #pragma unroll
    for (int otl = 0; otl < 4; otl++) {
        int o = (wid * 4 + otl) * 16 + lc;
        int hh = o >> 5, col = o & 31;
        float ebv = Eb[o];
        #pragma unroll
        for (int g = 0; g < 4; g++) {
            int e = 16 * g + lr4;
            #pragma unroll
            for (int jr = 0; jr < 4; jr++)
                sOutB[(e + jr) * SOB_S + hh * SOB_H + col] = f2bf(acc[g][otl][jr] + ebv);
        }
    }
    if (wid == 0 && lc < 8) {
        float webv = web[lc];
        #pragma unroll
        for (int g = 0; g < 4; g++) {
            int e = 16 * g + lr4;
            #pragma unroll
            for (int jr = 0; jr < 4; jr++)
                sBias[(e + jr) * 12 + lc] = accb[g][jr] + webv;
        }
    }
    __syncthreads();

    // ---- per-edge epilogue ----
    const int hp = t & 3;
    const int ge = eb0 + e_l;
    if (ge < NE) {
        const float4* K4 = (const float4*)(Kh + (size_t)sIdx * 128);
        const float4* Q4 = (const float4*)(Qh + (size_t)dIdx * 128);
        const float inv_s4  = 0.5f;
        const float inv_s12 = 0.28867513459481288f;
        #pragma unroll
        for (int hi = 0; hi < 2; hi++) {
            int hh = 2 * hp + hi;
            float eb = sBias[e_l * 12 + hh];
            float4 kf[4], qf[4];
            #pragma unroll
            for (int j = 0; j < 4; j++) { kf[j] = K4[hh * 4 + j]; qf[j] = Q4[hh * 4 + j]; }
            float sem = kf[0].x*qf[0].x + kf[0].y*qf[0].y + kf[0].z*qf[0].z + kf[0].w*qf[0].w;
            float stl = 0.0f;
            #pragma unroll
            for (int j = 1; j < 4; j++)
                stl += kf[j].x*qf[j].x + kf[j].y*qf[j].y + kf[j].z*qf[j].z + kf[j].w*qf[j].w;
            float logit = sem * inv_s4 + stl * inv_s12 + eb;
            logit = fminf(fmaxf(logit, -CLAMP), CLAMP);
            float ex = __expf(logit);
            exOut[(size_t)ge * 8 + hh] = ex;
            const ushort* srow = sOutB + e_l * SOB_S + hh * SOB_H;
            #pragma unroll
            for (int u = 0; u < 4; u++) {
                ushort4 ua = *(const ushort4*)(srow + 4 * u);
                ushort4 ub = *(const ushort4*)(srow + 16 + 4 * u);
                float4 A = make_float4(bf2f(ua.x), bf2f(ua.y), bf2f(ua.z), bf2f(ua.w));
                float4 B = make_float4(bf2f(ub.x), bf2f(ub.y), bf2f(ub.z), bf2f(ub.w));
                float4 kq = make_float4(kf[u].x + qf[u].x, kf[u].y + qf[u].y,
                                        kf[u].z + qf[u].z, kf[u].w + qf[u].w);
                f32x4 o;
                float v;
                v = kq.x * A.x; o[0] = copysignf(sqrtf(fabsf(v)), v) + B.x;
                v = kq.y * A.y; o[1] = copysignf(sqrtf(fabsf(v)), v) + B.y;
                v = kq.z * A.z; o[2] = copysignf(sqrtf(fabsf(v)), v) + B.z;
                v = kq.w * A.w; o[3] = copysignf(sqrtf(fabsf(v)), v) + B.w;
                __builtin_nontemporal_store(o, (f32x4*)(wE + (size_t)ge * 128 + hh * 16 + 4 * u));
            }
        }
    }
}

// ---------------------------------------------------------------------------
// CSR build (unchanged)
// ---------------------------------------------------------------------------
__global__ __launch_bounds__(256) void count_kernel(
    const int* __restrict__ dstI, int* __restrict__ cnt)
{
    int e = blockIdx.x * 256 + threadIdx.x;
    if (e < NE) atomicAdd(&cnt[dstI[e]], 1);
}

__global__ __launch_bounds__(1024) void block_scan_kernel(
    const int* __restrict__ cnt, int* __restrict__ rowstart, int* __restrict__ bsum)
{
    __shared__ int sbuf[1024];
    const int b = blockIdx.x, t = threadIdx.x;
    const int i = b * 1024 + t;
    sbuf[t] = (i < N) ? cnt[i] : 0;
    __syncthreads();
    for (int off = 1; off < 1024; off <<= 1) {
        int xv = sbuf[t];
        int yv = (t >= off) ? sbuf[t - off] : 0;
        __syncthreads();
        sbuf[t] = xv + yv;
        __syncthreads();
    }
    if (i < N) rowstart[i + 1] = sbuf[t];
    if (t == 1023) bsum[b] = sbuf[1023];
}

__global__ void scan_totals_kernel(int* __restrict__ bsum, int nb)
{
    if (threadIdx.x == 0 && blockIdx.x == 0) {
        int run = 0;
        for (int b = 0; b < nb; b++) { int v = bsum[b]; bsum[b] = run; run += v; }
    }
}

__global__ __launch_bounds__(1024) void add_offsets_kernel(
    const int* __restrict__ bsum, int* __restrict__ rowstart)
{
    const int b = blockIdx.x, t = threadIdx.x;
    const int i = b * 1024 + t;
    if (i < N) rowstart[i + 1] += bsum[b];
    if (b == 0 && t == 0) rowstart[0] = 0;
}

__global__ __launch_bounds__(256) void scatter_kernel(
    const int* __restrict__ dstI, const int* __restrict__ rowstart,
    int* __restrict__ cursor, int* __restrict__ elist)
{
    int e = blockIdx.x * 256 + threadIdx.x;
    if (e >= NE) return;
    int d = dstI[e];
    int pos = atomicAdd(&cursor[d], 1);
    elist[rowstart[d] + pos] = e;
}

// ---------------------------------------------------------------------------
// K3: gather-based wV (unchanged)
// ---------------------------------------------------------------------------
__global__ __launch_bounds__(256) void wv_kernel(
    const int* __restrict__ srcI, const int* __restrict__ elist,
    const int* __restrict__ rowstart, const float* __restrict__ Vh,
    const float* __restrict__ exOut, float* __restrict__ wV)
{
    const int dd = blockIdx.x * 2 + (threadIdx.x >> 7);
    const int o  = threadIdx.x & 127;
    if (dd >= N) return;
    const int h  = o >> 4;
    const int st = rowstart[dd];
    const int en = rowstart[dd + 1];
    float den = 0.0f, num = 0.0f;
    int i = st;
    for (; i + 2 <= en; i += 2) {
        int e0 = elist[i], e1 = elist[i + 1];
        int s0 = srcI[e0], s1 = srcI[e1];
        float ex0 = exOut[(size_t)e0 * 8 + h];
        float ex1 = exOut[(size_t)e1 * 8 + h];
        float v0 = Vh[(size_t)s0 * 128 + o];
        float v1 = Vh[(size_t)s1 * 128 + o];
        num = fmaf(v0, ex0, num);
        num = fmaf(v1, ex1, num);
        den += ex0 + ex1;
    }
    if (i < en) {
        int e0 = elist[i];
        int s0 = srcI[e0];
        float ex0 = exOut[(size_t)e0 * 8 + h];
        num = fmaf(Vh[(size_t)s0 * 128 + o], ex0, num);
        den += ex0;
    }
    wV[(size_t)dd * 128 + o] = num / (den + 1e-16f);
}

// ---------------------------------------------------------------------------
extern "C" void kernel_launch(void* const* d_in, const int* in_sizes, int n_in,
                              void* d_out, int out_size, void* d_ws, size_t ws_size,
                              hipStream_t stream)
{
    const float* x         = (const float*)d_in[0];
    const int*   edge_idx  = (const int*)d_in[1];
    const float* rrwp      = (const float*)d_in[2];
    const float* edge_attr = (const float*)d_in[3];
    const float* Qw        = (const float*)d_in[4];
    const float* Qb        = (const float*)d_in[5];
    const float* Kw        = (const float*)d_in[6];
    const float* Kb        = (const float*)d_in[7];
    const float* Vw        = (const float*)d_in[8];
    const float* Vb        = (const float*)d_in[9];
    const float* Ew        = (const float*)d_in[10];
    const float* Eb        = (const float*)d_in[11];
    const float* wew       = (const float*)d_in[12];
    const float* web       = (const float*)d_in[13];
    const float* Wang      = (const float*)d_in[14];

    const int* srcI = edge_idx;
    const int* dstI = edge_idx + NE;

    float* wV = (float*)d_out;                       // N * 128
    float* wE = wV + (size_t)N * 128;                // NE * 128

    ushort* EwHiF = (ushort*)d_ws;                   // 34816 bf16
    ushort* EwLoF = EwHiF + 34816;                   // 34816
    ushort* QWHiF = EwLoF + 34816;                   // 49152
    ushort* QWLoF = QWHiF + 49152;                   // 49152
    float* Qh   = (float*)(QWLoF + 49152);
    float* Kh   = Qh + (size_t)N * 128;
    float* Vh   = Kh + (size_t)N * 128;
    float* exO  = Vh + (size_t)N * 128;              // NE*8
    int* cnt      = (int*)(exO + (size_t)NE * 8);    // N
    int* rowstart = cnt + N;                         // N+1
    int* cursor   = rowstart + (N + 1);              // N
    int* elist    = cursor + N;                      // NE
    int* bsum     = elist + NE;                      // 64

    const int NB_SCAN = (N + 1023) / 1024;           // 49

    hipMemsetAsync(cnt, 0, (size_t)N * sizeof(int), stream);
    hipMemsetAsync(cursor, 0, (size_t)N * sizeof(int), stream);

    prep_w_kernel<<<17, 256, 0, stream>>>(Ew, wew, EwHiF, EwLoF);
    prep_qkvw_kernel<<<24, 256, 0, stream>>>(Qw, Kw, Vw, QWHiF, QWLoF);

    qkv_mfma_kernel<<<(N + QNPB - 1) / QNPB, 256, 0, stream>>>(
        x, rrwp, QWHiF, QWLoF, Qb, Kb, Vb, Wang, Qh, Kh, Vh);

    count_kernel<<<(NE + 255) / 256, 256, 0, stream>>>(dstI, cnt);
    block_scan_kernel<<<NB_SCAN, 1024, 0, stream>>>(cnt, rowstart, bsum);
    scan_totals_kernel<<<1, 64, 0, stream>>>(bsum, NB_SCAN);
    add_offsets_kernel<<<NB_SCAN, 1024, 0, stream>>>(bsum, rowstart);
    scatter_kernel<<<(NE + 255) / 256, 256, 0, stream>>>(dstI, rowstart, cursor, elist);

    edge_gemm_kernel<<<(NE + 63) / 64, 256, 0, stream>>>(
        edge_attr, srcI, dstI, Qh, Kh, EwHiF, EwLoF, Eb, web, wE, exO);

    wv_kernel<<<(N + 1) / 2, 256, 0, stream>>>(
        srcI, elist, rowstart, Vh, exO, wV);
}

// Round 9
// 629.220 us; speedup vs baseline: 1.5350x; 1.5350x over previous
//
#include <hip/hip_runtime.h>
#include <hip/hip_bf16.h>
#include <math.h>

constexpr int N    = 50000;
constexpr int NE   = 500000;
constexpr int IN   = 128;
constexpr int H    = 8;
constexpr int D    = 16;
constexpr int DSEM = 4;
constexpr int KS   = 21;
constexpr float CLAMP = 5.0f;

typedef __attribute__((ext_vector_type(8))) __bf16 bf16x8;
typedef __attribute__((ext_vector_type(4))) float  f32x4;

__device__ inline f32x4 mfma16(bf16x8 a, bf16x8 b, f32x4 c) {
    return __builtin_amdgcn_mfma_f32_16x16x32_bf16(a, b, c, 0, 0, 0);
}

__device__ inline void split_bf16(float f, unsigned& hi, unsigned& lo) {
    unsigned u = __float_as_uint(f);
    hi = (u + 0x7FFFu + ((u >> 16) & 1u)) >> 16;
    float fl = f - __uint_as_float(hi << 16);
    unsigned ul = __float_as_uint(fl);
    lo = (ul + 0x7FFFu + ((ul >> 16) & 1u)) >> 16;
}

__device__ inline void split2(float a, float b, unsigned& hi, unsigned& lo) {
    unsigned ha, la, hb, lb;
    split_bf16(a, ha, la);
    split_bf16(b, hb, lb);
    hi = ha | (hb << 16);
    lo = la | (lb << 16);
}

__device__ inline ushort f2bf(float f) {
    unsigned u = __float_as_uint(f);
    return (ushort)((u + 0x7FFFu + ((u >> 16) & 1u)) >> 16);
}
__device__ inline float bf2f(ushort u) {
    return __uint_as_float(((unsigned)u) << 16);
}

// ---------------------------------------------------------------------------
// prep_w: split [Ew (256 rows); wew (8 rows); zeros (8 rows)] = 272x128 into
// bf16 hi/lo, fragment-linear.  17 o-tiles.
// ---------------------------------------------------------------------------
__global__ __launch_bounds__(256) void prep_w_kernel(
    const float* __restrict__ Ew, const float* __restrict__ wew,
    ushort* __restrict__ EwHiF, ushort* __restrict__ EwLoF)
{
    int tid = blockIdx.x * 256 + threadIdx.x;          // 0..4351
    int l  = tid & 63;
    int ks = (tid >> 6) & 3;
    int ot = tid >> 8;                                 // 0..16
    int row = 16 * ot + (l & 15);
    int col = 32 * ks + 8 * (l >> 4);
    float4 f0, f1;
    if (row < 256) {
        const float* src = Ew + (size_t)row * 128 + col;
        f0 = *(const float4*)(src);
        f1 = *(const float4*)(src + 4);
    } else if (row < 264) {
        const float* src = wew + (size_t)(row - 256) * 128 + col;
        f0 = *(const float4*)(src);
        f1 = *(const float4*)(src + 4);
    } else {
        f0 = f1 = make_float4(0.f, 0.f, 0.f, 0.f);
    }
    unsigned H0,L0,H1,L1,H2,L2,H3,L3;
    split2(f0.x, f0.y, H0, L0);
    split2(f0.z, f0.w, H1, L1);
    split2(f1.x, f1.y, H2, L2);
    split2(f1.z, f1.w, H3, L3);
    *(uint4*)(EwHiF + (size_t)tid * 8) = make_uint4(H0, H1, H2, H3);
    *(uint4*)(EwLoF + (size_t)tid * 8) = make_uint4(L0, L1, L2, L3);
}

// ---------------------------------------------------------------------------
// prep_qkvw: split concat(Qw,Kw,Vw) (384x128) into bf16 hi/lo, frag-linear.
// ---------------------------------------------------------------------------
__global__ __launch_bounds__(256) void prep_qkvw_kernel(
    const float* __restrict__ Qw, const float* __restrict__ Kw,
    const float* __restrict__ Vw,
    ushort* __restrict__ WHiF, ushort* __restrict__ WLoF)
{
    int tid = blockIdx.x * 256 + threadIdx.x;          // 0..6143
    int l  = tid & 63;
    int ks = (tid >> 6) & 3;
    int ot = tid >> 8;                                 // 0..23
    int row = 16 * ot + (l & 15);                      // 0..383
    int col = 32 * ks + 8 * (l >> 4);
    const float* wrow = (row < 128) ? (Qw + (size_t)row * 128)
                      : (row < 256) ? (Kw + (size_t)(row - 128) * 128)
                                    : (Vw + (size_t)(row - 256) * 128);
    const float* src = wrow + col;
    float4 f0 = *(const float4*)(src);
    float4 f1 = *(const float4*)(src + 4);
    unsigned H0,L0,H1,L1,H2,L2,H3,L3;
    split2(f0.x, f0.y, H0, L0);
    split2(f0.z, f0.w, H1, L1);
    split2(f1.x, f1.y, H2, L2);
    split2(f1.z, f1.w, H3, L3);
    *(uint4*)(WHiF + (size_t)tid * 8) = make_uint4(H0, H1, H2, H3);
    *(uint4*)(WLoF + (size_t)tid * 8) = make_uint4(L0, L1, L2, L3);
}

// ---------------------------------------------------------------------------
// K1: QKV split-bf16 MFMA + RoPE.  32 nodes/block, W direct global->reg.
// (unchanged — known good)
// ---------------------------------------------------------------------------
constexpr int QNPB   = 32;
constexpr int QA_HI  = 0;
constexpr int QA_LO  = 8192;
constexpr int QSO_S  = 388;
constexpr int QSRR_OFF = 49664;
constexpr int QSC_OFF  = 52736;
constexpr int QSS_OFF  = 58880;
constexpr int Q_LDS    = 65024;

__global__ __launch_bounds__(256, 2) void qkv_mfma_kernel(
    const float* __restrict__ x, const float* __restrict__ rrwp,
    const ushort* __restrict__ WHiF, const ushort* __restrict__ WLoF,
    const float* __restrict__ Qb, const float* __restrict__ Kb,
    const float* __restrict__ Vb, const float* __restrict__ Wang,
    float* __restrict__ Qh, float* __restrict__ Kh, float* __restrict__ Vh)
{
    __shared__ __align__(16) char smem[Q_LDS];

    const int t    = threadIdx.x;
    const int wid  = t >> 6;
    const int lane = t & 63;
    const int nb0  = blockIdx.x * QNPB;

    float* srr = (float*)(smem + QSRR_OFF);
    float* scc = (float*)(smem + QSC_OFF);
    float* sss = (float*)(smem + QSS_OFF);

    for (int i = t; i < QNPB * KS; i += 256) {
        int nl = i / KS, k = i % KS;
        int n = nb0 + nl;
        srr[nl * 24 + k] = (n < N) ? rrwp[(size_t)n * KS + k] : 0.0f;
    }

    {
        const int se = t >> 3, sq = t & 7;
        const int sn = nb0 + se;
        const int g = se >> 4, sr = se & 15;
        const int cs2 = sq >> 1, lb = 2 * (sq & 1);
        const int abase = ((g * 4 + cs2) * 64 + lb * 16 + sr) * 16;
        float4 v0, v1, v2, v3;
        if (sn < N) {
            const float4* ar = (const float4*)(x + (size_t)sn * 128 + sq * 16);
            v0 = ar[0]; v1 = ar[1]; v2 = ar[2]; v3 = ar[3];
        } else {
            v0 = v1 = v2 = v3 = make_float4(0.f, 0.f, 0.f, 0.f);
        }
        unsigned H0,L0,H1,L1,H2,L2,H3,L3,H4,L4,H5,L5,H6,L6,H7,L7;
        split2(v0.x, v0.y, H0, L0); split2(v0.z, v0.w, H1, L1);
        split2(v1.x, v1.y, H2, L2); split2(v1.z, v1.w, H3, L3);
        split2(v2.x, v2.y, H4, L4); split2(v2.z, v2.w, H5, L5);
        split2(v3.x, v3.y, H6, L6); split2(v3.z, v3.w, H7, L7);
        *(uint4*)(smem + QA_HI + abase)       = make_uint4(H0, H1, H2, H3);
        *(uint4*)(smem + QA_HI + abase + 256) = make_uint4(H4, H5, H6, H7);
        *(uint4*)(smem + QA_LO + abase)       = make_uint4(L0, L1, L2, L3);
        *(uint4*)(smem + QA_LO + abase + 256) = make_uint4(L4, L5, L6, L7);
    }
    __syncthreads();

    f32x4 acc[2][6];
    #pragma unroll
    for (int g = 0; g < 2; g++)
        #pragma unroll
        for (int o = 0; o < 6; o++)
            acc[g][o] = (f32x4){0.f, 0.f, 0.f, 0.f};

    #pragma unroll
    for (int cs2 = 0; cs2 < 4; cs2++) {
        bf16x8 Ah[2], Al[2];
        #pragma unroll
        for (int g = 0; g < 2; g++) {
            int off = ((g * 4 + cs2) * 64 + lane) * 16;
            Ah[g] = *(const bf16x8*)(smem + QA_HI + off);
            Al[g] = *(const bf16x8*)(smem + QA_LO + off);
        }
        #pragma unroll
        for (int otl = 0; otl < 6; otl++) {
            int ot = wid * 6 + otl;
            size_t woff = (size_t)((ot * 4 + cs2) * 64 + lane) * 16;
            bf16x8 Bh = *(const bf16x8*)((const char*)WHiF + woff);
            bf16x8 Bl = *(const bf16x8*)((const char*)WLoF + woff);
            #pragma unroll
            for (int g = 0; g < 2; g++) {
                acc[g][otl] = mfma16(Ah[g], Bh, acc[g][otl]);
                acc[g][otl] = mfma16(Al[g], Bh, acc[g][otl]);
                acc[g][otl] = mfma16(Ah[g], Bl, acc[g][otl]);
            }
        }
    }
    __syncthreads();

    float* sout = (float*)smem;
    const int lr4 = (lane >> 4) * 4;
    const int lc  = lane & 15;
    #pragma unroll
    for (int otl = 0; otl < 6; otl++) {
        int o = (wid * 6 + otl) * 16 + lc;
        float bv = (o < 128) ? Qb[o] : (o < 256) ? Kb[o - 128] : Vb[o - 256];
        #pragma unroll
        for (int g = 0; g < 2; g++) {
            int e = 16 * g + lr4;
            #pragma unroll
            for (int jr = 0; jr < 4; jr++)
                sout[(e + jr) * QSO_S + o] = acc[g][otl][jr] + bv;
        }
    }
    __syncthreads();

    for (int i = t; i < QNPB * 48; i += 256) {
        int nl = i / 48, a = i % 48;
        int h = a / 6, r = a % 6;
        float av = 0.0f;
        #pragma unroll
        for (int k = 0; k < KS; k++)
            av = fmaf(srr[nl * 24 + k], Wang[(size_t)(h * KS + k) * 6 + r], av);
        float sv, cv;
        sincosf(av, &sv, &cv);
        scc[nl * 48 + a] = cv;
        sss[nl * 48 + a] = sv;
    }
    __syncthreads();

    for (int i = t; i < QNPB * 384; i += 256) {
        int nl = i / 384, o = i % 384;
        int n = nb0 + nl;
        if (n >= N) continue;
        int mat = o >> 7;
        int oo  = o & 127;
        int h = oo >> 4, d = oo & 15;
        float val;
        if (mat == 2 || d < DSEM) {
            val = sout[nl * QSO_S + o];
        } else {
            int i2 = (d - DSEM) >> 1;
            float cv = scc[nl * 48 + h * 6 + i2];
            float sv = sss[nl * 48 + h * 6 + i2];
            int base = (mat << 7) + h * 16 + DSEM + 2 * i2;
            float xe = sout[nl * QSO_S + base];
            float xo = sout[nl * QSO_S + base + 1];
            val = ((d & 1) == 0) ? (xe * cv - xo * sv) : (xe * sv + xo * cv);
        }
        float* dp = (mat == 0) ? Qh : (mat == 1) ? Kh : Vh;
        dp[(size_t)n * 128 + oo] = val;
    }
}

// ---------------------------------------------------------------------------
// K2 v5 = round-6 structure (measured 373 us) + bf16 sOut ONLY.
//  - per-chunk staging with av[8] register prefetch (R6)
//  - W fragments direct global->reg per k-slice (R6)
//  - e_bias as 17th MFMA o-tile, wave 0 (R6)
//  - launch_bounds(256,2): no VGPR cap pressure, no spills (R6)
//  - bf16 sOut/sBias: LDS 77.8 -> 39.9 KB -> HW can fit 3 blocks/CU
//  - regular (non-NT) stores
// ---------------------------------------------------------------------------
constexpr int AHI_OFF = 0;        // [4 g][2 ks2][64 l][16 B] = 8192
constexpr int ALO_OFF = 8192;     // ends 16384
constexpr int SOB_S   = 288;      // ushorts per edge row (8 heads x 36)
constexpr int SOB_H   = 36;
constexpr int SBIAS_OFF = 64 * SOB_S * 2;             // 36864
constexpr int EDG_LDS   = SBIAS_OFF + 64 * 12 * 4;    // 39936

__global__ __launch_bounds__(256, 2) void edge_gemm_kernel(
    const float* __restrict__ edge_attr,
    const int* __restrict__ srcI, const int* __restrict__ dstI,
    const float* __restrict__ Qh, const float* __restrict__ Kh,
    const ushort* __restrict__ EwHiF, const ushort* __restrict__ EwLoF,
    const float* __restrict__ Eb, const float* __restrict__ web,
    float* __restrict__ wE, float* __restrict__ exOut)
{
    __shared__ __align__(16) char smem[EDG_LDS];

    const int t    = threadIdx.x;
    const int wid  = t >> 6;
    const int lane = t & 63;
    const int eb0  = blockIdx.x * 64;

    // ---- early prefetch: edge_attr rows (both chunks) + epilogue indices ----
    const int se   = t >> 2;
    const int sq   = t & 3;
    const int sge  = eb0 + se;
    float4 av[8];
    {
        if (sge < NE) {
            const float4* ar = (const float4*)(edge_attr + (size_t)sge * 128 + sq * 16);
            #pragma unroll
            for (int j = 0; j < 4; j++) av[j] = ar[j];
            #pragma unroll
            for (int j = 0; j < 4; j++) av[4 + j] = ar[16 + j];
        } else {
            #pragma unroll
            for (int j = 0; j < 8; j++) av[j] = make_float4(0.f, 0.f, 0.f, 0.f);
        }
    }
    const int e_l = t >> 2;
    const int geC = (eb0 + e_l < NE) ? (eb0 + e_l) : (NE - 1);
    const int sIdx = srcI[geC];
    const int dIdx = dstI[geC];

    f32x4 acc[4][4];
    #pragma unroll
    for (int g = 0; g < 4; g++)
        #pragma unroll
        for (int o = 0; o < 4; o++)
            acc[g][o] = (f32x4){0.f, 0.f, 0.f, 0.f};
    f32x4 accb[4];
    #pragma unroll
    for (int g = 0; g < 4; g++) accb[g] = (f32x4){0.f, 0.f, 0.f, 0.f};

    const int sr   = se & 15;
    const int sg   = se >> 4;
    const int sks2 = sq >> 1;
    const int slb  = 2 * (sq & 1);
    const int abase = ((sg * 2 + sks2) * 64 + slb * 16 + sr) * 16;

    #pragma unroll 1
    for (int c = 0; c < 2; c++) {
        {
            const float4* vv = av + c * 4;
            unsigned H0,L0,H1,L1,H2,L2,H3,L3,H4,L4,H5,L5,H6,L6,H7,L7;
            split2(vv[0].x, vv[0].y, H0, L0); split2(vv[0].z, vv[0].w, H1, L1);
            split2(vv[1].x, vv[1].y, H2, L2); split2(vv[1].z, vv[1].w, H3, L3);
            split2(vv[2].x, vv[2].y, H4, L4); split2(vv[2].z, vv[2].w, H5, L5);
            split2(vv[3].x, vv[3].y, H6, L6); split2(vv[3].z, vv[3].w, H7, L7);
            *(uint4*)(smem + AHI_OFF + abase)       = make_uint4(H0, H1, H2, H3);
            *(uint4*)(smem + AHI_OFF + abase + 256) = make_uint4(H4, H5, H6, H7);
            *(uint4*)(smem + ALO_OFF + abase)       = make_uint4(L0, L1, L2, L3);
            *(uint4*)(smem + ALO_OFF + abase + 256) = make_uint4(L4, L5, L6, L7);
        }
        __syncthreads();

        #pragma unroll
        for (int ks2 = 0; ks2 < 2; ks2++) {
            bf16x8 Wh[4], Wl[4];
            #pragma unroll
            for (int otl = 0; otl < 4; otl++) {
                int ot = wid * 4 + otl;
                size_t woff = (size_t)(((ot * 4 + c * 2 + ks2) * 64 + lane)) * 16;
                Wh[otl] = *(const bf16x8*)((const char*)EwHiF + woff);
                Wl[otl] = *(const bf16x8*)((const char*)EwLoF + woff);
            }
            bf16x8 Bbh, Bbl;
            if (wid == 0) {
                size_t woff = (size_t)(((16 * 4 + c * 2 + ks2) * 64 + lane)) * 16;
                Bbh = *(const bf16x8*)((const char*)EwHiF + woff);
                Bbl = *(const bf16x8*)((const char*)EwLoF + woff);
            }
            bf16x8 Ah[4], Al[4];
            #pragma unroll
            for (int g = 0; g < 4; g++) {
                int off = ((g * 2 + ks2) * 64 + lane) * 16;
                Ah[g] = *(const bf16x8*)(smem + AHI_OFF + off);
                Al[g] = *(const bf16x8*)(smem + ALO_OFF + off);
            }
            #pragma unroll
            for (int otl = 0; otl < 4; otl++) {
                #pragma unroll
                for (int g = 0; g < 4; g++) {
                    acc[g][otl] = mfma16(Ah[g], Wh[otl], acc[g][otl]);
                    acc[g][otl] = mfma16(Al[g], Wh[otl], acc[g][otl]);
                    acc[g][otl] = mfma16(Ah[g], Wl[otl], acc[g][otl]);
                }
            }
            if (wid == 0) {
                #pragma unroll
                for (int g = 0; g < 4; g++) {
                    accb[g] = mfma16(Ah[g], Bbh, accb[g]);
                    accb[g] = mfma16(Al[g], Bbh, accb[g]);
                    accb[g] = mfma16(Ah[g], Bbl, accb[g]);
                }
            }
        }
        __syncthreads();
    }

    // ---- acc -> bf16 sOut (+Eb), accb -> sBias (+web) ----
    ushort* sOutB = (ushort*)smem;
    float*  sBias = (float*)(smem + SBIAS_OFF);
    const int lr4 = (lane >> 4) * 4;
    const int lc  = lane & 15;
    #pragma unroll
    for (int otl = 0; otl < 4; otl++) {
        int o = (wid * 4 + otl) * 16 + lc;
        int hh = o >> 5, col = o & 31;
        float ebv = Eb[o];
        #pragma unroll
        for (int g = 0; g < 4; g++) {
            int e = 16 * g + lr4;
            #pragma unroll
            for (int jr = 0; jr < 4; jr++)
                sOutB[(e + jr) * SOB_S + hh * SOB_H + col] = f2bf(acc[g][otl][jr] + ebv);
        }
    }
    if (wid == 0 && lc < 8) {
        float webv = web[lc];
        #pragma unroll
        for (int g = 0; g < 4; g++) {
            int e = 16 * g + lr4;
            #pragma unroll
            for (int jr = 0; jr < 4; jr++)
                sBias[(e + jr) * 12 + lc] = accb[g][jr] + webv;
        }
    }
    __syncthreads();

    // ---- per-edge epilogue ----
    const int hp = t & 3;
    const int ge = eb0 + e_l;
    if (ge < NE) {
        const float4* K4 = (const float4*)(Kh + (size_t)sIdx * 128);
        const float4* Q4 = (const float4*)(Qh + (size_t)dIdx * 128);
        const float inv_s4  = 0.5f;
        const float inv_s12 = 0.28867513459481288f;
        #pragma unroll
        for (int hi = 0; hi < 2; hi++) {
            int hh = 2 * hp + hi;
            float eb = sBias[e_l * 12 + hh];
            float4 kf[4], qf[4];
            #pragma unroll
            for (int j = 0; j < 4; j++) { kf[j] = K4[hh * 4 + j]; qf[j] = Q4[hh * 4 + j]; }
            float sem = kf[0].x*qf[0].x + kf[0].y*qf[0].y + kf[0].z*qf[0].z + kf[0].w*qf[0].w;
            float stl = 0.0f;
            #pragma unroll
            for (int j = 1; j < 4; j++)
                stl += kf[j].x*qf[j].x + kf[j].y*qf[j].y + kf[j].z*qf[j].z + kf[j].w*qf[j].w;
            float logit = sem * inv_s4 + stl * inv_s12 + eb;
            logit = fminf(fmaxf(logit, -CLAMP), CLAMP);
            float ex = __expf(logit);
            exOut[(size_t)ge * 8 + hh] = ex;
            const ushort* srow = sOutB + e_l * SOB_S + hh * SOB_H;
            #pragma unroll
            for (int u = 0; u < 4; u++) {
                ushort4 ua = *(const ushort4*)(srow + 4 * u);
                ushort4 ub = *(const ushort4*)(srow + 16 + 4 * u);
                float4 A = make_float4(bf2f(ua.x), bf2f(ua.y), bf2f(ua.z), bf2f(ua.w));
                float4 B = make_float4(bf2f(ub.x), bf2f(ub.y), bf2f(ub.z), bf2f(ub.w));
                float4 kq = make_float4(kf[u].x + qf[u].x, kf[u].y + qf[u].y,
                                        kf[u].z + qf[u].z, kf[u].w + qf[u].w);
                float4 o;
                float v;
                v = kq.x * A.x; o.x = copysignf(sqrtf(fabsf(v)), v) + B.x;
                v = kq.y * A.y; o.y = copysignf(sqrtf(fabsf(v)), v) + B.y;
                v = kq.z * A.z; o.z = copysignf(sqrtf(fabsf(v)), v) + B.z;
                v = kq.w * A.w; o.w = copysignf(sqrtf(fabsf(v)), v) + B.w;
                *(float4*)(wE + (size_t)ge * 128 + hh * 16 + 4 * u) = o;
            }
        }
    }
}

// ---------------------------------------------------------------------------
// CSR build (unchanged)
// ---------------------------------------------------------------------------
__global__ __launch_bounds__(256) void count_kernel(
    const int* __restrict__ dstI, int* __restrict__ cnt)
{
    int e = blockIdx.x * 256 + threadIdx.x;
    if (e < NE) atomicAdd(&cnt[dstI[e]], 1);
}

__global__ __launch_bounds__(1024) void block_scan_kernel(
    const int* __restrict__ cnt, int* __restrict__ rowstart, int* __restrict__ bsum)
{
    __shared__ int sbuf[1024];
    const int b = blockIdx.x, t = threadIdx.x;
    const int i = b * 1024 + t;
    sbuf[t] = (i < N) ? cnt[i] : 0;
    __syncthreads();
    for (int off = 1; off < 1024; off <<= 1) {
        int xv = sbuf[t];
        int yv = (t >= off) ? sbuf[t - off] : 0;
        __syncthreads();
        sbuf[t] = xv + yv;
        __syncthreads();
    }
    if (i < N) rowstart[i + 1] = sbuf[t];
    if (t == 1023) bsum[b] = sbuf[1023];
}

__global__ void scan_totals_kernel(int* __restrict__ bsum, int nb)
{
    if (threadIdx.x == 0 && blockIdx.x == 0) {
        int run = 0;
        for (int b = 0; b < nb; b++) { int v = bsum[b]; bsum[b] = run; run += v; }
    }
}

__global__ __launch_bounds__(1024) void add_offsets_kernel(
    const int* __restrict__ bsum, int* __restrict__ rowstart)
{
    const int b = blockIdx.x, t = threadIdx.x;
    const int i = b * 1024 + t;
    if (i < N) rowstart[i + 1] += bsum[b];
    if (b == 0 && t == 0) rowstart[0] = 0;
}

__global__ __launch_bounds__(256) void scatter_kernel(
    const int* __restrict__ dstI, const int* __restrict__ rowstart,
    int* __restrict__ cursor, int* __restrict__ elist)
{
    int e = blockIdx.x * 256 + threadIdx.x;
    if (e >= NE) return;
    int d = dstI[e];
    int pos = atomicAdd(&cursor[d], 1);
    elist[rowstart[d] + pos] = e;
}

// ---------------------------------------------------------------------------
// K3: gather-based wV (unchanged)
// ---------------------------------------------------------------------------
__global__ __launch_bounds__(256) void wv_kernel(
    const int* __restrict__ srcI, const int* __restrict__ elist,
    const int* __restrict__ rowstart, const float* __restrict__ Vh,
    const float* __restrict__ exOut, float* __restrict__ wV)
{
    const int dd = blockIdx.x * 2 + (threadIdx.x >> 7);
    const int o  = threadIdx.x & 127;
    if (dd >= N) return;
    const int h  = o >> 4;
    const int st = rowstart[dd];
    const int en = rowstart[dd + 1];
    float den = 0.0f, num = 0.0f;
    int i = st;
    for (; i + 2 <= en; i += 2) {
        int e0 = elist[i], e1 = elist[i + 1];
        int s0 = srcI[e0], s1 = srcI[e1];
        float ex0 = exOut[(size_t)e0 * 8 + h];
        float ex1 = exOut[(size_t)e1 * 8 + h];
        float v0 = Vh[(size_t)s0 * 128 + o];
        float v1 = Vh[(size_t)s1 * 128 + o];
        num = fmaf(v0, ex0, num);
        num = fmaf(v1, ex1, num);
        den += ex0 + ex1;
    }
    if (i < en) {
        int e0 = elist[i];
        int s0 = srcI[e0];
        float ex0 = exOut[(size_t)e0 * 8 + h];
        num = fmaf(Vh[(size_t)s0 * 128 + o], ex0, num);
        den += ex0;
    }
    wV[(size_t)dd * 128 + o] = num / (den + 1e-16f);
}

// ---------------------------------------------------------------------------
extern "C" void kernel_launch(void* const* d_in, const int* in_sizes, int n_in,
                              void* d_out, int out_size, void* d_ws, size_t ws_size,
                              hipStream_t stream)
{
    const float* x         = (const float*)d_in[0];
    const int*   edge_idx  = (const int*)d_in[1];
    const float* rrwp      = (const float*)d_in[2];
    const float* edge_attr = (const float*)d_in[3];
    const float* Qw        = (const float*)d_in[4];
    const float* Qb        = (const float*)d_in[5];
    const float* Kw        = (const float*)d_in[6];
    const float* Kb        = (const float*)d_in[7];
    const float* Vw        = (const float*)d_in[8];
    const float* Vb        = (const float*)d_in[9];
    const float* Ew        = (const float*)d_in[10];
    const float* Eb        = (const float*)d_in[11];
    const float* wew       = (const float*)d_in[12];
    const float* web       = (const float*)d_in[13];
    const float* Wang      = (const float*)d_in[14];

    const int* srcI = edge_idx;
    const int* dstI = edge_idx + NE;

    float* wV = (float*)d_out;                       // N * 128
    float* wE = wV + (size_t)N * 128;                // NE * 128

    ushort* EwHiF = (ushort*)d_ws;                   // 34816 bf16
    ushort* EwLoF = EwHiF + 34816;                   // 34816
    ushort* QWHiF = EwLoF + 34816;                   // 49152
    ushort* QWLoF = QWHiF + 49152;                   // 49152
    float* Qh   = (float*)(QWLoF + 49152);
    float* Kh   = Qh + (size_t)N * 128;
    float* Vh   = Kh + (size_t)N * 128;
    float* exO  = Vh + (size_t)N * 128;              // NE*8
    int* cnt      = (int*)(exO + (size_t)NE * 8);    // N
    int* rowstart = cnt + N;                         // N+1
    int* cursor   = rowstart + (N + 1);              // N
    int* elist    = cursor + N;                      // NE
    int* bsum     = elist + NE;                      // 64

    const int NB_SCAN = (N + 1023) / 1024;           // 49

    hipMemsetAsync(cnt, 0, (size_t)N * sizeof(int), stream);
    hipMemsetAsync(cursor, 0, (size_t)N * sizeof(int), stream);

    prep_w_kernel<<<17, 256, 0, stream>>>(Ew, wew, EwHiF, EwLoF);
    prep_qkvw_kernel<<<24, 256, 0, stream>>>(Qw, Kw, Vw, QWHiF, QWLoF);

    qkv_mfma_kernel<<<(N + QNPB - 1) / QNPB, 256, 0, stream>>>(
        x, rrwp, QWHiF, QWLoF, Qb, Kb, Vb, Wang, Qh, Kh, Vh);

    count_kernel<<<(NE + 255) / 256, 256, 0, stream>>>(dstI, cnt);
    block_scan_kernel<<<NB_SCAN, 1024, 0, stream>>>(cnt, rowstart, bsum);
    scan_totals_kernel<<<1, 64, 0, stream>>>(bsum, NB_SCAN);
    add_offsets_kernel<<<NB_SCAN, 1024, 0, stream>>>(bsum, rowstart);
    scatter_kernel<<<(NE + 255) / 256, 256, 0, stream>>>(dstI, rowstart, cursor, elist);

    edge_gemm_kernel<<<(NE + 63) / 64, 256, 0, stream>>>(
        edge_attr, srcI, dstI, Qh, Kh, EwHiF, EwLoF, Eb, web, wE, exO);

    wv_kernel<<<(N + 1) / 2, 256, 0, stream>>>(
        srcI, elist, rowstart, Vh, exO, wV);
}

// Round 11
// 624.941 us; speedup vs baseline: 1.5455x; 1.0068x over previous
//
#include <hip/hip_runtime.h>
#include <hip/hip_bf16.h>
#include <math.h>

constexpr int N    = 50000;
constexpr int NE   = 500000;
constexpr int IN   = 128;
constexpr int H    = 8;
constexpr int D    = 16;
constexpr int DSEM = 4;
constexpr int KS   = 21;
constexpr float CLAMP = 5.0f;

typedef __attribute__((ext_vector_type(8))) __bf16 bf16x8;
typedef __attribute__((ext_vector_type(4))) float  f32x4;

__device__ inline f32x4 mfma16(bf16x8 a, bf16x8 b, f32x4 c) {
    return __builtin_amdgcn_mfma_f32_16x16x32_bf16(a, b, c, 0, 0, 0);
}

__device__ inline void split_bf16(float f, unsigned& hi, unsigned& lo) {
    unsigned u = __float_as_uint(f);
    hi = (u + 0x7FFFu + ((u >> 16) & 1u)) >> 16;
    float fl = f - __uint_as_float(hi << 16);
    unsigned ul = __float_as_uint(fl);
    lo = (ul + 0x7FFFu + ((ul >> 16) & 1u)) >> 16;
}

__device__ inline void split2(float a, float b, unsigned& hi, unsigned& lo) {
    unsigned ha, la, hb, lb;
    split_bf16(a, ha, la);
    split_bf16(b, hb, lb);
    hi = ha | (hb << 16);
    lo = la | (lb << 16);
}

__device__ inline ushort f2bf(float f) {
    unsigned u = __float_as_uint(f);
    return (ushort)((u + 0x7FFFu + ((u >> 16) & 1u)) >> 16);
}
__device__ inline float bf2f(ushort u) {
    return __uint_as_float(((unsigned)u) << 16);
}

// ---------------------------------------------------------------------------
// prep_w: split [Ew (256 rows); wew (8 rows); zeros (8 rows)] = 272x128 into
// bf16 hi/lo, fragment-linear.  17 o-tiles.
// ---------------------------------------------------------------------------
__global__ __launch_bounds__(256) void prep_w_kernel(
    const float* __restrict__ Ew, const float* __restrict__ wew,
    ushort* __restrict__ EwHiF, ushort* __restrict__ EwLoF)
{
    int tid = blockIdx.x * 256 + threadIdx.x;          // 0..4351
    int l  = tid & 63;
    int ks = (tid >> 6) & 3;
    int ot = tid >> 8;                                 // 0..16
    int row = 16 * ot + (l & 15);
    int col = 32 * ks + 8 * (l >> 4);
    float4 f0, f1;
    if (row < 256) {
        const float* src = Ew + (size_t)row * 128 + col;
        f0 = *(const float4*)(src);
        f1 = *(const float4*)(src + 4);
    } else if (row < 264) {
        const float* src = wew + (size_t)(row - 256) * 128 + col;
        f0 = *(const float4*)(src);
        f1 = *(const float4*)(src + 4);
    } else {
        f0 = f1 = make_float4(0.f, 0.f, 0.f, 0.f);
    }
    unsigned H0,L0,H1,L1,H2,L2,H3,L3;
    split2(f0.x, f0.y, H0, L0);
    split2(f0.z, f0.w, H1, L1);
    split2(f1.x, f1.y, H2, L2);
    split2(f1.z, f1.w, H3, L3);
    *(uint4*)(EwHiF + (size_t)tid * 8) = make_uint4(H0, H1, H2, H3);
    *(uint4*)(EwLoF + (size_t)tid * 8) = make_uint4(L0, L1, L2, L3);
}

// ---------------------------------------------------------------------------
// prep_qkvw: split concat(Qw,Kw,Vw) (384x128) into bf16 hi/lo, frag-linear.
// ---------------------------------------------------------------------------
__global__ __launch_bounds__(256) void prep_qkvw_kernel(
    const float* __restrict__ Qw, const float* __restrict__ Kw,
    const float* __restrict__ Vw,
    ushort* __restrict__ WHiF, ushort* __restrict__ WLoF)
{
    int tid = blockIdx.x * 256 + threadIdx.x;          // 0..6143
    int l  = tid & 63;
    int ks = (tid >> 6) & 3;
    int ot = tid >> 8;                                 // 0..23
    int row = 16 * ot + (l & 15);                      // 0..383
    int col = 32 * ks + 8 * (l >> 4);
    const float* wrow = (row < 128) ? (Qw + (size_t)row * 128)
                      : (row < 256) ? (Kw + (size_t)(row - 128) * 128)
                                    : (Vw + (size_t)(row - 256) * 128);
    const float* src = wrow + col;
    float4 f0 = *(const float4*)(src);
    float4 f1 = *(const float4*)(src + 4);
    unsigned H0,L0,H1,L1,H2,L2,H3,L3;
    split2(f0.x, f0.y, H0, L0);
    split2(f0.z, f0.w, H1, L1);
    split2(f1.x, f1.y, H2, L2);
    split2(f1.z, f1.w, H3, L3);
    *(uint4*)(WHiF + (size_t)tid * 8) = make_uint4(H0, H1, H2, H3);
    *(uint4*)(WLoF + (size_t)tid * 8) = make_uint4(L0, L1, L2, L3);
}

// ---------------------------------------------------------------------------
// K1: QKV split-bf16 MFMA + RoPE.  Qh/Kh fp32 (feed sqrt-amplified wE path),
// Vh bf16 (feeds only the tolerant wV average).
// ---------------------------------------------------------------------------
constexpr int QNPB   = 32;
constexpr int QA_HI  = 0;
constexpr int QA_LO  = 8192;
constexpr int QSO_S  = 388;
constexpr int QSRR_OFF = 49664;
constexpr int QSC_OFF  = 52736;
constexpr int QSS_OFF  = 58880;
constexpr int Q_LDS    = 65024;

__global__ __launch_bounds__(256, 2) void qkv_mfma_kernel(
    const float* __restrict__ x, const float* __restrict__ rrwp,
    const ushort* __restrict__ WHiF, const ushort* __restrict__ WLoF,
    const float* __restrict__ Qb, const float* __restrict__ Kb,
    const float* __restrict__ Vb, const float* __restrict__ Wang,
    float* __restrict__ Qh, float* __restrict__ Kh, ushort* __restrict__ Vh)
{
    __shared__ __align__(16) char smem[Q_LDS];

    const int t    = threadIdx.x;
    const int wid  = t >> 6;
    const int lane = t & 63;
    const int nb0  = blockIdx.x * QNPB;

    float* srr = (float*)(smem + QSRR_OFF);
    float* scc = (float*)(smem + QSC_OFF);
    float* sss = (float*)(smem + QSS_OFF);

    for (int i = t; i < QNPB * KS; i += 256) {
        int nl = i / KS, k = i % KS;
        int n = nb0 + nl;
        srr[nl * 24 + k] = (n < N) ? rrwp[(size_t)n * KS + k] : 0.0f;
    }

    {
        const int se = t >> 3, sq = t & 7;
        const int sn = nb0 + se;
        const int g = se >> 4, sr = se & 15;
        const int cs2 = sq >> 1, lb = 2 * (sq & 1);
        const int abase = ((g * 4 + cs2) * 64 + lb * 16 + sr) * 16;
        float4 v0, v1, v2, v3;
        if (sn < N) {
            const float4* ar = (const float4*)(x + (size_t)sn * 128 + sq * 16);
            v0 = ar[0]; v1 = ar[1]; v2 = ar[2]; v3 = ar[3];
        } else {
            v0 = v1 = v2 = v3 = make_float4(0.f, 0.f, 0.f, 0.f);
        }
        unsigned H0,L0,H1,L1,H2,L2,H3,L3,H4,L4,H5,L5,H6,L6,H7,L7;
        split2(v0.x, v0.y, H0, L0); split2(v0.z, v0.w, H1, L1);
        split2(v1.x, v1.y, H2, L2); split2(v1.z, v1.w, H3, L3);
        split2(v2.x, v2.y, H4, L4); split2(v2.z, v2.w, H5, L5);
        split2(v3.x, v3.y, H6, L6); split2(v3.z, v3.w, H7, L7);
        *(uint4*)(smem + QA_HI + abase)       = make_uint4(H0, H1, H2, H3);
        *(uint4*)(smem + QA_HI + abase + 256) = make_uint4(H4, H5, H6, H7);
        *(uint4*)(smem + QA_LO + abase)       = make_uint4(L0, L1, L2, L3);
        *(uint4*)(smem + QA_LO + abase + 256) = make_uint4(L4, L5, L6, L7);
    }
    __syncthreads();

    f32x4 acc[2][6];
    #pragma unroll
    for (int g = 0; g < 2; g++)
        #pragma unroll
        for (int o = 0; o < 6; o++)
            acc[g][o] = (f32x4){0.f, 0.f, 0.f, 0.f};

    #pragma unroll
    for (int cs2 = 0; cs2 < 4; cs2++) {
        bf16x8 Ah[2], Al[2];
        #pragma unroll
        for (int g = 0; g < 2; g++) {
            int off = ((g * 4 + cs2) * 64 + lane) * 16;
            Ah[g] = *(const bf16x8*)(smem + QA_HI + off);
            Al[g] = *(const bf16x8*)(smem + QA_LO + off);
        }
        #pragma unroll
        for (int otl = 0; otl < 6; otl++) {
            int ot = wid * 6 + otl;
            size_t woff = (size_t)((ot * 4 + cs2) * 64 + lane) * 16;
            bf16x8 Bh = *(const bf16x8*)((const char*)WHiF + woff);
            bf16x8 Bl = *(const bf16x8*)((const char*)WLoF + woff);
            #pragma unroll
            for (int g = 0; g < 2; g++) {
                acc[g][otl] = mfma16(Ah[g], Bh, acc[g][otl]);
                acc[g][otl] = mfma16(Al[g], Bh, acc[g][otl]);
                acc[g][otl] = mfma16(Ah[g], Bl, acc[g][otl]);
            }
        }
    }
    __syncthreads();

    float* sout = (float*)smem;
    const int lr4 = (lane >> 4) * 4;
    const int lc  = lane & 15;
    #pragma unroll
    for (int otl = 0; otl < 6; otl++) {
        int o = (wid * 6 + otl) * 16 + lc;
        float bv = (o < 128) ? Qb[o] : (o < 256) ? Kb[o - 128] : Vb[o - 256];
        #pragma unroll
        for (int g = 0; g < 2; g++) {
            int e = 16 * g + lr4;
            #pragma unroll
            for (int jr = 0; jr < 4; jr++)
                sout[(e + jr) * QSO_S + o] = acc[g][otl][jr] + bv;
        }
    }
    __syncthreads();

    for (int i = t; i < QNPB * 48; i += 256) {
        int nl = i / 48, a = i % 48;
        int h = a / 6, r = a % 6;
        float av = 0.0f;
        #pragma unroll
        for (int k = 0; k < KS; k++)
            av = fmaf(srr[nl * 24 + k], Wang[(size_t)(h * KS + k) * 6 + r], av);
        float sv, cv;
        sincosf(av, &sv, &cv);
        scc[nl * 48 + a] = cv;
        sss[nl * 48 + a] = sv;
    }
    __syncthreads();

    for (int i = t; i < QNPB * 384; i += 256) {
        int nl = i / 384, o = i % 384;
        int n = nb0 + nl;
        if (n >= N) continue;
        int mat = o >> 7;
        int oo  = o & 127;
        int h = oo >> 4, d = oo & 15;
        float val;
        if (mat == 2 || d < DSEM) {
            val = sout[nl * QSO_S + o];
        } else {
            int i2 = (d - DSEM) >> 1;
            float cv = scc[nl * 48 + h * 6 + i2];
            float sv = sss[nl * 48 + h * 6 + i2];
            int base = (mat << 7) + h * 16 + DSEM + 2 * i2;
            float xe = sout[nl * QSO_S + base];
            float xo = sout[nl * QSO_S + base + 1];
            val = ((d & 1) == 0) ? (xe * cv - xo * sv) : (xe * sv + xo * cv);
        }
        if (mat == 2) {
            Vh[(size_t)n * 128 + oo] = f2bf(val);
        } else {
            float* dp = (mat == 0) ? Qh : Kh;
            dp[(size_t)n * 128 + oo] = val;
        }
    }
}

// ---------------------------------------------------------------------------
// K2: R9 structure exactly (fp32 K/Q epilogue gathers, bf16 sOut).
// ---------------------------------------------------------------------------
constexpr int AHI_OFF = 0;        // [4 g][2 ks2][64 l][16 B] = 8192
constexpr int ALO_OFF = 8192;     // ends 16384
constexpr int SOB_S   = 288;      // ushorts per edge row (8 heads x 36)
constexpr int SOB_H   = 36;
constexpr int SBIAS_OFF = 64 * SOB_S * 2;             // 36864
constexpr int EDG_LDS   = SBIAS_OFF + 64 * 12 * 4;    // 39936

__global__ __launch_bounds__(256, 2) void edge_gemm_kernel(
    const float* __restrict__ edge_attr,
    const int* __restrict__ srcI, const int* __restrict__ dstI,
    const float* __restrict__ Qh, const float* __restrict__ Kh,
    const ushort* __restrict__ EwHiF, const ushort* __restrict__ EwLoF,
    const float* __restrict__ Eb, const float* __restrict__ web,
    float* __restrict__ wE, float* __restrict__ exOut)
{
    __shared__ __align__(16) char smem[EDG_LDS];

    const int t    = threadIdx.x;
    const int wid  = t >> 6;
    const int lane = t & 63;
    const int eb0  = blockIdx.x * 64;

    const int se   = t >> 2;
    const int sq   = t & 3;
    const int sge  = eb0 + se;
    float4 av[8];
    {
        if (sge < NE) {
            const float4* ar = (const float4*)(edge_attr + (size_t)sge * 128 + sq * 16);
            #pragma unroll
            for (int j = 0; j < 4; j++) av[j] = ar[j];
            #pragma unroll
            for (int j = 0; j < 4; j++) av[4 + j] = ar[16 + j];
        } else {
            #pragma unroll
            for (int j = 0; j < 8; j++) av[j] = make_float4(0.f, 0.f, 0.f, 0.f);
        }
    }
    const int e_l = t >> 2;
    const int geC = (eb0 + e_l < NE) ? (eb0 + e_l) : (NE - 1);
    const int sIdx = srcI[geC];
    const int dIdx = dstI[geC];

    f32x4 acc[4][4];
    #pragma unroll
    for (int g = 0; g < 4; g++)
        #pragma unroll
        for (int o = 0; o < 4; o++)
            acc[g][o] = (f32x4){0.f, 0.f, 0.f, 0.f};
    f32x4 accb[4];
    #pragma unroll
    for (int g = 0; g < 4; g++) accb[g] = (f32x4){0.f, 0.f, 0.f, 0.f};

    const int sr   = se & 15;
    const int sg   = se >> 4;
    const int sks2 = sq >> 1;
    const int slb  = 2 * (sq & 1);
    const int abase = ((sg * 2 + sks2) * 64 + slb * 16 + sr) * 16;

    #pragma unroll 1
    for (int c = 0; c < 2; c++) {
        {
            const float4* vv = av + c * 4;
            unsigned H0,L0,H1,L1,H2,L2,H3,L3,H4,L4,H5,L5,H6,L6,H7,L7;
            split2(vv[0].x, vv[0].y, H0, L0); split2(vv[0].z, vv[0].w, H1, L1);
            split2(vv[1].x, vv[1].y, H2, L2); split2(vv[1].z, vv[1].w, H3, L3);
            split2(vv[2].x, vv[2].y, H4, L4); split2(vv[2].z, vv[2].w, H5, L5);
            split2(vv[3].x, vv[3].y, H6, L6); split2(vv[3].z, vv[3].w, H7, L7);
            *(uint4*)(smem + AHI_OFF + abase)       = make_uint4(H0, H1, H2, H3);
            *(uint4*)(smem + AHI_OFF + abase + 256) = make_uint4(H4, H5, H6, H7);
            *(uint4*)(smem + ALO_OFF + abase)       = make_uint4(L0, L1, L2, L3);
            *(uint4*)(smem + ALO_OFF + abase + 256) = make_uint4(L4, L5, L6, L7);
        }
        __syncthreads();

        #pragma unroll
        for (int ks2 = 0; ks2 < 2; ks2++) {
            bf16x8 Wh[4], Wl[4];
            #pragma unroll
            for (int otl = 0; otl < 4; otl++) {
                int ot = wid * 4 + otl;
                size_t woff = (size_t)(((ot * 4 + c * 2 + ks2) * 64 + lane)) * 16;
                Wh[otl] = *(const bf16x8*)((const char*)EwHiF + woff);
                Wl[otl] = *(const bf16x8*)((const char*)EwLoF + woff);
            }
            bf16x8 Bbh, Bbl;
            if (wid == 0) {
                size_t woff = (size_t)(((16 * 4 + c * 2 + ks2) * 64 + lane)) * 16;
                Bbh = *(const bf16x8*)((const char*)EwHiF + woff);
                Bbl = *(const bf16x8*)((const char*)EwLoF + woff);
            }
            bf16x8 Ah[4], Al[4];
            #pragma unroll
            for (int g = 0; g < 4; g++) {
                int off = ((g * 2 + ks2) * 64 + lane) * 16;
                Ah[g] = *(const bf16x8*)(smem + AHI_OFF + off);
                Al[g] = *(const bf16x8*)(smem + ALO_OFF + off);
            }
            #pragma unroll
            for (int otl = 0; otl < 4; otl++) {
                #pragma unroll
                for (int g = 0; g < 4; g++) {
                    acc[g][otl] = mfma16(Ah[g], Wh[otl], acc[g][otl]);
                    acc[g][otl] = mfma16(Al[g], Wh[otl], acc[g][otl]);
                    acc[g][otl] = mfma16(Ah[g], Wl[otl], acc[g][otl]);
                }
            }
            if (wid == 0) {
                #pragma unroll
                for (int g = 0; g < 4; g++) {
                    accb[g] = mfma16(Ah[g], Bbh, accb[g]);
                    accb[g] = mfma16(Al[g], Bbh, accb[g]);
                    accb[g] = mfma16(Ah[g], Bbl, accb[g]);
                }
            }
        }
        __syncthreads();
    }

    // ---- acc -> bf16 sOut (+Eb), accb -> sBias (+web) ----
    ushort* sOutB = (ushort*)smem;
    float*  sBias = (float*)(smem + SBIAS_OFF);
    const int lr4 = (lane >> 4) * 4;
    const int lc  = lane & 15;
    #pragma unroll
    for (int otl = 0; otl < 4; otl++) {
        int o = (wid * 4 + otl) * 16 + lc;
        int hh = o >> 5, col = o & 31;
        float ebv = Eb[o];
        #pragma unroll
        for (int g = 0; g < 4; g++) {
            int e = 16 * g + lr4;
            #pragma unroll
            for (int jr = 0; jr < 4; jr++)
                sOutB[(e + jr) * SOB_S + hh * SOB_H + col] = f2bf(acc[g][otl][jr] + ebv);
        }
    }
    if (wid == 0 && lc < 8) {
        float webv = web[lc];
        #pragma unroll
        for (int g = 0; g < 4; g++) {
            int e = 16 * g + lr4;
            #pragma unroll
            for (int jr = 0; jr < 4; jr++)
                sBias[(e + jr) * 12 + lc] = accb[g][jr] + webv;
        }
    }
    __syncthreads();

    // ---- per-edge epilogue (fp32 K/Q gathers) ----
    const int hp = t & 3;
    const int ge = eb0 + e_l;
    if (ge < NE) {
        const float4* K4 = (const float4*)(Kh + (size_t)sIdx * 128);
        const float4* Q4 = (const float4*)(Qh + (size_t)dIdx * 128);
        const float inv_s4  = 0.5f;
        const float inv_s12 = 0.28867513459481288f;
        #pragma unroll
        for (int hi = 0; hi < 2; hi++) {
            int hh = 2 * hp + hi;
            float eb = sBias[e_l * 12 + hh];
            float4 kf[4], qf[4];
            #pragma unroll
            for (int j = 0; j < 4; j++) { kf[j] = K4[hh * 4 + j]; qf[j] = Q4[hh * 4 + j]; }
            float sem = kf[0].x*qf[0].x + kf[0].y*qf[0].y + kf[0].z*qf[0].z + kf[0].w*qf[0].w;
            float stl = 0.0f;
            #pragma unroll
            for (int j = 1; j < 4; j++)
                stl += kf[j].x*qf[j].x + kf[j].y*qf[j].y + kf[j].z*qf[j].z + kf[j].w*qf[j].w;
            float logit = sem * inv_s4 + stl * inv_s12 + eb;
            logit = fminf(fmaxf(logit, -CLAMP), CLAMP);
            float ex = __expf(logit);
            exOut[(size_t)ge * 8 + hh] = ex;
            const ushort* srow = sOutB + e_l * SOB_S + hh * SOB_H;
            #pragma unroll
            for (int u = 0; u < 4; u++) {
                ushort4 ua = *(const ushort4*)(srow + 4 * u);
                ushort4 ub = *(const ushort4*)(srow + 16 + 4 * u);
                float4 A = make_float4(bf2f(ua.x), bf2f(ua.y), bf2f(ua.z), bf2f(ua.w));
                float4 B = make_float4(bf2f(ub.x), bf2f(ub.y), bf2f(ub.z), bf2f(ub.w));
                float4 kq = make_float4(kf[u].x + qf[u].x, kf[u].y + qf[u].y,
                                        kf[u].z + qf[u].z, kf[u].w + qf[u].w);
                float4 o;
                float v;
                v = kq.x * A.x; o.x = copysignf(sqrtf(fabsf(v)), v) + B.x;
                v = kq.y * A.y; o.y = copysignf(sqrtf(fabsf(v)), v) + B.y;
                v = kq.z * A.z; o.z = copysignf(sqrtf(fabsf(v)), v) + B.z;
                v = kq.w * A.w; o.w = copysignf(sqrtf(fabsf(v)), v) + B.w;
                *(float4*)(wE + (size_t)ge * 128 + hh * 16 + 4 * u) = o;
            }
        }
    }
}

// ---------------------------------------------------------------------------
// CSR build (unchanged)
// ---------------------------------------------------------------------------
__global__ __launch_bounds__(256) void count_kernel(
    const int* __restrict__ dstI, int* __restrict__ cnt)
{
    int e = blockIdx.x * 256 + threadIdx.x;
    if (e < NE) atomicAdd(&cnt[dstI[e]], 1);
}

__global__ __launch_bounds__(1024) void block_scan_kernel(
    const int* __restrict__ cnt, int* __restrict__ rowstart, int* __restrict__ bsum)
{
    __shared__ int sbuf[1024];
    const int b = blockIdx.x, t = threadIdx.x;
    const int i = b * 1024 + t;
    sbuf[t] = (i < N) ? cnt[i] : 0;
    __syncthreads();
    for (int off = 1; off < 1024; off <<= 1) {
        int xv = sbuf[t];
        int yv = (t >= off) ? sbuf[t - off] : 0;
        __syncthreads();
        sbuf[t] = xv + yv;
        __syncthreads();
    }
    if (i < N) rowstart[i + 1] = sbuf[t];
    if (t == 1023) bsum[b] = sbuf[1023];
}

__global__ void scan_totals_kernel(int* __restrict__ bsum, int nb)
{
    if (threadIdx.x == 0 && blockIdx.x == 0) {
        int run = 0;
        for (int b = 0; b < nb; b++) { int v = bsum[b]; bsum[b] = run; run += v; }
    }
}

__global__ __launch_bounds__(1024) void add_offsets_kernel(
    const int* __restrict__ bsum, int* __restrict__ rowstart)
{
    const int b = blockIdx.x, t = threadIdx.x;
    const int i = b * 1024 + t;
    if (i < N) rowstart[i + 1] += bsum[b];
    if (b == 0 && t == 0) rowstart[0] = 0;
}

__global__ __launch_bounds__(256) void scatter_kernel(
    const int* __restrict__ dstI, const int* __restrict__ rowstart,
    int* __restrict__ cursor, int* __restrict__ elist)
{
    int e = blockIdx.x * 256 + threadIdx.x;
    if (e >= NE) return;
    int d = dstI[e];
    int pos = atomicAdd(&cursor[d], 1);
    elist[rowstart[d] + pos] = e;
}

// ---------------------------------------------------------------------------
// K3: gather-based wV (Vh bf16)
// ---------------------------------------------------------------------------
__global__ __launch_bounds__(256) void wv_kernel(
    const int* __restrict__ srcI, const int* __restrict__ elist,
    const int* __restrict__ rowstart, const ushort* __restrict__ Vh,
    const float* __restrict__ exOut, float* __restrict__ wV)
{
    const int dd = blockIdx.x * 2 + (threadIdx.x >> 7);
    const int o  = threadIdx.x & 127;
    if (dd >= N) return;
    const int h  = o >> 4;
    const int st = rowstart[dd];
    const int en = rowstart[dd + 1];
    float den = 0.0f, num = 0.0f;
    int i = st;
    for (; i + 2 <= en; i += 2) {
        int e0 = elist[i], e1 = elist[i + 1];
        int s0 = srcI[e0], s1 = srcI[e1];
        float ex0 = exOut[(size_t)e0 * 8 + h];
        float ex1 = exOut[(size_t)e1 * 8 + h];
        float v0 = bf2f(Vh[(size_t)s0 * 128 + o]);
        float v1 = bf2f(Vh[(size_t)s1 * 128 + o]);
        num = fmaf(v0, ex0, num);
        num = fmaf(v1, ex1, num);
        den += ex0 + ex1;
    }
    if (i < en) {
        int e0 = elist[i];
        int s0 = srcI[e0];
        float ex0 = exOut[(size_t)e0 * 8 + h];
        num = fmaf(bf2f(Vh[(size_t)s0 * 128 + o]), ex0, num);
        den += ex0;
    }
    wV[(size_t)dd * 128 + o] = num / (den + 1e-16f);
}

// ---------------------------------------------------------------------------
extern "C" void kernel_launch(void* const* d_in, const int* in_sizes, int n_in,
                              void* d_out, int out_size, void* d_ws, size_t ws_size,
                              hipStream_t stream)
{
    const float* x         = (const float*)d_in[0];
    const int*   edge_idx  = (const int*)d_in[1];
    const float* rrwp      = (const float*)d_in[2];
    const float* edge_attr = (const float*)d_in[3];
    const float* Qw        = (const float*)d_in[4];
    const float* Qb        = (const float*)d_in[5];
    const float* Kw        = (const float*)d_in[6];
    const float* Kb        = (const float*)d_in[7];
    const float* Vw        = (const float*)d_in[8];
    const float* Vb        = (const float*)d_in[9];
    const float* Ew        = (const float*)d_in[10];
    const float* Eb        = (const float*)d_in[11];
    const float* wew       = (const float*)d_in[12];
    const float* web       = (const float*)d_in[13];
    const float* Wang      = (const float*)d_in[14];

    const int* srcI = edge_idx;
    const int* dstI = edge_idx + NE;

    float* wV = (float*)d_out;                       // N * 128
    float* wE = wV + (size_t)N * 128;                // NE * 128

    ushort* EwHiF = (ushort*)d_ws;                   // 34816 bf16
    ushort* EwLoF = EwHiF + 34816;                   // 34816
    ushort* QWHiF = EwLoF + 34816;                   // 49152
    ushort* QWLoF = QWHiF + 49152;                   // 49152
    ushort* VhB = QWLoF + 49152;                     // N*128 bf16
    float* Qh   = (float*)(VhB + (size_t)N * 128);   // N*128 fp32
    float* Kh   = Qh + (size_t)N * 128;
    float* exO  = Kh + (size_t)N * 128;              // NE*8
    int* cnt      = (int*)(exO + (size_t)NE * 8);    // N
    int* rowstart = cnt + N;                         // N+1
    int* cursor   = rowstart + (N + 1);              // N
    int* elist    = cursor + N;                      // NE
    int* bsum     = elist + NE;                      // 64

    const int NB_SCAN = (N + 1023) / 1024;           // 49

    hipMemsetAsync(cnt, 0, (size_t)N * sizeof(int), stream);
    hipMemsetAsync(cursor, 0, (size_t)N * sizeof(int), stream);

    prep_w_kernel<<<17, 256, 0, stream>>>(Ew, wew, EwHiF, EwLoF);
    prep_qkvw_kernel<<<24, 256, 0, stream>>>(Qw, Kw, Vw, QWHiF, QWLoF);

    qkv_mfma_kernel<<<(N + QNPB - 1) / QNPB, 256, 0, stream>>>(
        x, rrwp, QWHiF, QWLoF, Qb, Kb, Vb, Wang, Qh, Kh, VhB);

    count_kernel<<<(NE + 255) / 256, 256, 0, stream>>>(dstI, cnt);
    block_scan_kernel<<<NB_SCAN, 1024, 0, stream>>>(cnt, rowstart, bsum);
    scan_totals_kernel<<<1, 64, 0, stream>>>(bsum, NB_SCAN);
    add_offsets_kernel<<<NB_SCAN, 1024, 0, stream>>>(bsum, rowstart);
    scatter_kernel<<<(NE + 255) / 256, 256, 0, stream>>>(dstI, rowstart, cursor, elist);

    edge_gemm_kernel<<<(NE + 63) / 64, 256, 0, stream>>>(
        edge_attr, srcI, dstI, Qh, Kh, EwHiF, EwLoF, Eb, web, wE, exO);

    wv_kernel<<<(N + 1) / 2, 256, 0, stream>>>(
        srcI, elist, rowstart, VhB, exO, wV);
}

// Round 12
// 618.832 us; speedup vs baseline: 1.5608x; 1.0099x over previous
//
#include <hip/hip_runtime.h>
#include <hip/hip_bf16.h>
#include <math.h>

constexpr int N    = 50000;
constexpr int NE   = 500000;
constexpr int IN   = 128;
constexpr int H    = 8;
constexpr int D    = 16;
constexpr int DSEM = 4;
constexpr int KS   = 21;
constexpr float CLAMP = 5.0f;

typedef __attribute__((ext_vector_type(8))) __bf16 bf16x8;
typedef __attribute__((ext_vector_type(4))) float  f32x4;

__device__ inline f32x4 mfma16(bf16x8 a, bf16x8 b, f32x4 c) {
    return __builtin_amdgcn_mfma_f32_16x16x32_bf16(a, b, c, 0, 0, 0);
}

__device__ inline void split_bf16(float f, unsigned& hi, unsigned& lo) {
    unsigned u = __float_as_uint(f);
    hi = (u + 0x7FFFu + ((u >> 16) & 1u)) >> 16;
    float fl = f - __uint_as_float(hi << 16);
    unsigned ul = __float_as_uint(fl);
    lo = (ul + 0x7FFFu + ((ul >> 16) & 1u)) >> 16;
}

__device__ inline void split2(float a, float b, unsigned& hi, unsigned& lo) {
    unsigned ha, la, hb, lb;
    split_bf16(a, ha, la);
    split_bf16(b, hb, lb);
    hi = ha | (hb << 16);
    lo = la | (lb << 16);
}

__device__ inline ushort f2bf(float f) {
    unsigned u = __float_as_uint(f);
    return (ushort)((u + 0x7FFFu + ((u >> 16) & 1u)) >> 16);
}
__device__ inline float bf2f(ushort u) {
    return __uint_as_float(((unsigned)u) << 16);
}

// ---------------------------------------------------------------------------
// prep_w: split [Ew (256 rows); wew (8 rows); zeros (8 rows)] = 272x128 into
// bf16 hi/lo, fragment-linear.  17 o-tiles.
// ---------------------------------------------------------------------------
__global__ __launch_bounds__(256) void prep_w_kernel(
    const float* __restrict__ Ew, const float* __restrict__ wew,
    ushort* __restrict__ EwHiF, ushort* __restrict__ EwLoF)
{
    int tid = blockIdx.x * 256 + threadIdx.x;          // 0..4351
    int l  = tid & 63;
    int ks = (tid >> 6) & 3;
    int ot = tid >> 8;                                 // 0..16
    int row = 16 * ot + (l & 15);
    int col = 32 * ks + 8 * (l >> 4);
    float4 f0, f1;
    if (row < 256) {
        const float* src = Ew + (size_t)row * 128 + col;
        f0 = *(const float4*)(src);
        f1 = *(const float4*)(src + 4);
    } else if (row < 264) {
        const float* src = wew + (size_t)(row - 256) * 128 + col;
        f0 = *(const float4*)(src);
        f1 = *(const float4*)(src + 4);
    } else {
        f0 = f1 = make_float4(0.f, 0.f, 0.f, 0.f);
    }
    unsigned H0,L0,H1,L1,H2,L2,H3,L3;
    split2(f0.x, f0.y, H0, L0);
    split2(f0.z, f0.w, H1, L1);
    split2(f1.x, f1.y, H2, L2);
    split2(f1.z, f1.w, H3, L3);
    *(uint4*)(EwHiF + (size_t)tid * 8) = make_uint4(H0, H1, H2, H3);
    *(uint4*)(EwLoF + (size_t)tid * 8) = make_uint4(L0, L1, L2, L3);
}

// ---------------------------------------------------------------------------
// prep_qkvw: split concat(Qw,Kw,Vw) (384x128) into bf16 hi/lo, frag-linear.
// ---------------------------------------------------------------------------
__global__ __launch_bounds__(256) void prep_qkvw_kernel(
    const float* __restrict__ Qw, const float* __restrict__ Kw,
    const float* __restrict__ Vw,
    ushort* __restrict__ WHiF, ushort* __restrict__ WLoF)
{
    int tid = blockIdx.x * 256 + threadIdx.x;          // 0..6143
    int l  = tid & 63;
    int ks = (tid >> 6) & 3;
    int ot = tid >> 8;                                 // 0..23
    int row = 16 * ot + (l & 15);                      // 0..383
    int col = 32 * ks + 8 * (l >> 4);
    const float* wrow = (row < 128) ? (Qw + (size_t)row * 128)
                      : (row < 256) ? (Kw + (size_t)(row - 128) * 128)
                                    : (Vw + (size_t)(row - 256) * 128);
    const float* src = wrow + col;
    float4 f0 = *(const float4*)(src);
    float4 f1 = *(const float4*)(src + 4);
    unsigned H0,L0,H1,L1,H2,L2,H3,L3;
    split2(f0.x, f0.y, H0, L0);
    split2(f0.z, f0.w, H1, L1);
    split2(f1.x, f1.y, H2, L2);
    split2(f1.z, f1.w, H3, L3);
    *(uint4*)(WHiF + (size_t)tid * 8) = make_uint4(H0, H1, H2, H3);
    *(uint4*)(WLoF + (size_t)tid * 8) = make_uint4(L0, L1, L2, L3);
}

// ---------------------------------------------------------------------------
// K1: QKV split-bf16 MFMA + RoPE.  Qh/Kh fp32, Vh bf16. (unchanged)
// ---------------------------------------------------------------------------
constexpr int QNPB   = 32;
constexpr int QA_HI  = 0;
constexpr int QA_LO  = 8192;
constexpr int QSO_S  = 388;
constexpr int QSRR_OFF = 49664;
constexpr int QSC_OFF  = 52736;
constexpr int QSS_OFF  = 58880;
constexpr int Q_LDS    = 65024;

__global__ __launch_bounds__(256, 2) void qkv_mfma_kernel(
    const float* __restrict__ x, const float* __restrict__ rrwp,
    const ushort* __restrict__ WHiF, const ushort* __restrict__ WLoF,
    const float* __restrict__ Qb, const float* __restrict__ Kb,
    const float* __restrict__ Vb, const float* __restrict__ Wang,
    float* __restrict__ Qh, float* __restrict__ Kh, ushort* __restrict__ Vh)
{
    __shared__ __align__(16) char smem[Q_LDS];

    const int t    = threadIdx.x;
    const int wid  = t >> 6;
    const int lane = t & 63;
    const int nb0  = blockIdx.x * QNPB;

    float* srr = (float*)(smem + QSRR_OFF);
    float* scc = (float*)(smem + QSC_OFF);
    float* sss = (float*)(smem + QSS_OFF);

    for (int i = t; i < QNPB * KS; i += 256) {
        int nl = i / KS, k = i % KS;
        int n = nb0 + nl;
        srr[nl * 24 + k] = (n < N) ? rrwp[(size_t)n * KS + k] : 0.0f;
    }

    {
        const int se = t >> 3, sq = t & 7;
        const int sn = nb0 + se;
        const int g = se >> 4, sr = se & 15;
        const int cs2 = sq >> 1, lb = 2 * (sq & 1);
        const int abase = ((g * 4 + cs2) * 64 + lb * 16 + sr) * 16;
        float4 v0, v1, v2, v3;
        if (sn < N) {
            const float4* ar = (const float4*)(x + (size_t)sn * 128 + sq * 16);
            v0 = ar[0]; v1 = ar[1]; v2 = ar[2]; v3 = ar[3];
        } else {
            v0 = v1 = v2 = v3 = make_float4(0.f, 0.f, 0.f, 0.f);
        }
        unsigned H0,L0,H1,L1,H2,L2,H3,L3,H4,L4,H5,L5,H6,L6,H7,L7;
        split2(v0.x, v0.y, H0, L0); split2(v0.z, v0.w, H1, L1);
        split2(v1.x, v1.y, H2, L2); split2(v1.z, v1.w, H3, L3);
        split2(v2.x, v2.y, H4, L4); split2(v2.z, v2.w, H5, L5);
        split2(v3.x, v3.y, H6, L6); split2(v3.z, v3.w, H7, L7);
        *(uint4*)(smem + QA_HI + abase)       = make_uint4(H0, H1, H2, H3);
        *(uint4*)(smem + QA_HI + abase + 256) = make_uint4(H4, H5, H6, H7);
        *(uint4*)(smem + QA_LO + abase)       = make_uint4(L0, L1, L2, L3);
        *(uint4*)(smem + QA_LO + abase + 256) = make_uint4(L4, L5, L6, L7);
    }
    __syncthreads();

    f32x4 acc[2][6];
    #pragma unroll
    for (int g = 0; g < 2; g++)
        #pragma unroll
        for (int o = 0; o < 6; o++)
            acc[g][o] = (f32x4){0.f, 0.f, 0.f, 0.f};

    #pragma unroll
    for (int cs2 = 0; cs2 < 4; cs2++) {
        bf16x8 Ah[2], Al[2];
        #pragma unroll
        for (int g = 0; g < 2; g++) {
            int off = ((g * 4 + cs2) * 64 + lane) * 16;
            Ah[g] = *(const bf16x8*)(smem + QA_HI + off);
            Al[g] = *(const bf16x8*)(smem + QA_LO + off);
        }
        #pragma unroll
        for (int otl = 0; otl < 6; otl++) {
            int ot = wid * 6 + otl;
            size_t woff = (size_t)((ot * 4 + cs2) * 64 + lane) * 16;
            bf16x8 Bh = *(const bf16x8*)((const char*)WHiF + woff);
            bf16x8 Bl = *(const bf16x8*)((const char*)WLoF + woff);
            #pragma unroll
            for (int g = 0; g < 2; g++) {
                acc[g][otl] = mfma16(Ah[g], Bh, acc[g][otl]);
                acc[g][otl] = mfma16(Al[g], Bh, acc[g][otl]);
                acc[g][otl] = mfma16(Ah[g], Bl, acc[g][otl]);
            }
        }
    }
    __syncthreads();

    float* sout = (float*)smem;
    const int lr4 = (lane >> 4) * 4;
    const int lc  = lane & 15;
    #pragma unroll
    for (int otl = 0; otl < 6; otl++) {
        int o = (wid * 6 + otl) * 16 + lc;
        float bv = (o < 128) ? Qb[o] : (o < 256) ? Kb[o - 128] : Vb[o - 256];
        #pragma unroll
        for (int g = 0; g < 2; g++) {
            int e = 16 * g + lr4;
            #pragma unroll
            for (int jr = 0; jr < 4; jr++)
                sout[(e + jr) * QSO_S + o] = acc[g][otl][jr] + bv;
        }
    }
    __syncthreads();

    for (int i = t; i < QNPB * 48; i += 256) {
        int nl = i / 48, a = i % 48;
        int h = a / 6, r = a % 6;
        float av = 0.0f;
        #pragma unroll
        for (int k = 0; k < KS; k++)
            av = fmaf(srr[nl * 24 + k], Wang[(size_t)(h * KS + k) * 6 + r], av);
        float sv, cv;
        sincosf(av, &sv, &cv);
        scc[nl * 48 + a] = cv;
        sss[nl * 48 + a] = sv;
    }
    __syncthreads();

    for (int i = t; i < QNPB * 384; i += 256) {
        int nl = i / 384, o = i % 384;
        int n = nb0 + nl;
        if (n >= N) continue;
        int mat = o >> 7;
        int oo  = o & 127;
        int h = oo >> 4, d = oo & 15;
        float val;
        if (mat == 2 || d < DSEM) {
            val = sout[nl * QSO_S + o];
        } else {
            int i2 = (d - DSEM) >> 1;
            float cv = scc[nl * 48 + h * 6 + i2];
            float sv = sss[nl * 48 + h * 6 + i2];
            int base = (mat << 7) + h * 16 + DSEM + 2 * i2;
            float xe = sout[nl * QSO_S + base];
            float xo = sout[nl * QSO_S + base + 1];
            val = ((d & 1) == 0) ? (xe * cv - xo * sv) : (xe * sv + xo * cv);
        }
        if (mat == 2) {
            Vh[(size_t)n * 128 + oo] = f2bf(val);
        } else {
            float* dp = (mat == 0) ? Qh : Kh;
            dp[(size_t)n * 128 + oo] = val;
        }
    }
}

// ---------------------------------------------------------------------------
// K2: R11 structure, but edges processed in DST-SORTED order (elist):
// consecutive edges share dst -> Q gathers L1/L2-hit.  exS/srcS/dstS are
// position-indexed (sorted), so wv reads them sequentially.
// wE stays indexed by ORIGINAL edge id.
// ---------------------------------------------------------------------------
constexpr int AHI_OFF = 0;        // [4 g][2 ks2][64 l][16 B] = 8192
constexpr int ALO_OFF = 8192;     // ends 16384
constexpr int SOB_S   = 288;      // ushorts per edge row (8 heads x 36)
constexpr int SOB_H   = 36;
constexpr int SBIAS_OFF = 64 * SOB_S * 2;             // 36864
constexpr int EDG_LDS   = SBIAS_OFF + 64 * 12 * 4;    // 39936

__global__ __launch_bounds__(256, 2) void edge_gemm_kernel(
    const float* __restrict__ edge_attr,
    const int* __restrict__ elist,
    const int* __restrict__ srcS, const int* __restrict__ dstS,
    const float* __restrict__ Qh, const float* __restrict__ Kh,
    const ushort* __restrict__ EwHiF, const ushort* __restrict__ EwLoF,
    const float* __restrict__ Eb, const float* __restrict__ web,
    float* __restrict__ wE, float* __restrict__ exS)
{
    __shared__ __align__(16) char smem[EDG_LDS];

    const int t    = threadIdx.x;
    const int wid  = t >> 6;
    const int lane = t & 63;
    const int eb0  = blockIdx.x * 64;

    const int se   = t >> 2;
    const int sq   = t & 3;
    const int pos  = eb0 + se;
    const int posC = (pos < NE) ? pos : (NE - 1);
    const int ge   = (pos < NE) ? elist[pos] : -1;

    float4 av[8];
    {
        if (ge >= 0) {
            const float4* ar = (const float4*)(edge_attr + (size_t)ge * 128 + sq * 16);
            #pragma unroll
            for (int j = 0; j < 4; j++) av[j] = ar[j];
            #pragma unroll
            for (int j = 0; j < 4; j++) av[4 + j] = ar[16 + j];
        } else {
            #pragma unroll
            for (int j = 0; j < 8; j++) av[j] = make_float4(0.f, 0.f, 0.f, 0.f);
        }
    }
    const int e_l  = se;
    const int sIdx = srcS[posC];
    const int dIdx = dstS[posC];

    f32x4 acc[4][4];
    #pragma unroll
    for (int g = 0; g < 4; g++)
        #pragma unroll
        for (int o = 0; o < 4; o++)
            acc[g][o] = (f32x4){0.f, 0.f, 0.f, 0.f};
    f32x4 accb[4];
    #pragma unroll
    for (int g = 0; g < 4; g++) accb[g] = (f32x4){0.f, 0.f, 0.f, 0.f};

    const int sr   = se & 15;
    const int sg   = se >> 4;
    const int sks2 = sq >> 1;
    const int slb  = 2 * (sq & 1);
    const int abase = ((sg * 2 + sks2) * 64 + slb * 16 + sr) * 16;

    #pragma unroll 1
    for (int c = 0; c < 2; c++) {
        {
            const float4* vv = av + c * 4;
            unsigned H0,L0,H1,L1,H2,L2,H3,L3,H4,L4,H5,L5,H6,L6,H7,L7;
            split2(vv[0].x, vv[0].y, H0, L0); split2(vv[0].z, vv[0].w, H1, L1);
            split2(vv[1].x, vv[1].y, H2, L2); split2(vv[1].z, vv[1].w, H3, L3);
            split2(vv[2].x, vv[2].y, H4, L4); split2(vv[2].z, vv[2].w, H5, L5);
            split2(vv[3].x, vv[3].y, H6, L6); split2(vv[3].z, vv[3].w, H7, L7);
            *(uint4*)(smem + AHI_OFF + abase)       = make_uint4(H0, H1, H2, H3);
            *(uint4*)(smem + AHI_OFF + abase + 256) = make_uint4(H4, H5, H6, H7);
            *(uint4*)(smem + ALO_OFF + abase)       = make_uint4(L0, L1, L2, L3);
            *(uint4*)(smem + ALO_OFF + abase + 256) = make_uint4(L4, L5, L6, L7);
        }
        __syncthreads();

        #pragma unroll
        for (int ks2 = 0; ks2 < 2; ks2++) {
            bf16x8 Wh[4], Wl[4];
            #pragma unroll
            for (int otl = 0; otl < 4; otl++) {
                int ot = wid * 4 + otl;
                size_t woff = (size_t)(((ot * 4 + c * 2 + ks2) * 64 + lane)) * 16;
                Wh[otl] = *(const bf16x8*)((const char*)EwHiF + woff);
                Wl[otl] = *(const bf16x8*)((const char*)EwLoF + woff);
            }
            bf16x8 Bbh, Bbl;
            if (wid == 0) {
                size_t woff = (size_t)(((16 * 4 + c * 2 + ks2) * 64 + lane)) * 16;
                Bbh = *(const bf16x8*)((const char*)EwHiF + woff);
                Bbl = *(const bf16x8*)((const char*)EwLoF + woff);
            }
            bf16x8 Ah[4], Al[4];
            #pragma unroll
            for (int g = 0; g < 4; g++) {
                int off = ((g * 2 + ks2) * 64 + lane) * 16;
                Ah[g] = *(const bf16x8*)(smem + AHI_OFF + off);
                Al[g] = *(const bf16x8*)(smem + ALO_OFF + off);
            }
            #pragma unroll
            for (int otl = 0; otl < 4; otl++) {
                #pragma unroll
                for (int g = 0; g < 4; g++) {
                    acc[g][otl] = mfma16(Ah[g], Wh[otl], acc[g][otl]);
                    acc[g][otl] = mfma16(Al[g], Wh[otl], acc[g][otl]);
                    acc[g][otl] = mfma16(Ah[g], Wl[otl], acc[g][otl]);
                }
            }
            if (wid == 0) {
                #pragma unroll
                for (int g = 0; g < 4; g++) {
                    accb[g] = mfma16(Ah[g], Bbh, accb[g]);
                    accb[g] = mfma16(Al[g], Bbh, accb[g]);
                    accb[g] = mfma16(Ah[g], Bbl, accb[g]);
                }
            }
        }
        __syncthreads();
    }

    // ---- acc -> bf16 sOut (+Eb), accb -> sBias (+web) ----
    ushort* sOutB = (ushort*)smem;
    float*  sBias = (float*)(smem + SBIAS_OFF);
    const int lr4 = (lane >> 4) * 4;
    const int lc  = lane & 15;
    #pragma unroll
    for (int otl = 0; otl < 4; otl++) {
        int o = (wid * 4 + otl) * 16 + lc;
        int hh = o >> 5, col = o & 31;
        float ebv = Eb[o];
        #pragma unroll
        for (int g = 0; g < 4; g++) {
            int e = 16 * g + lr4;
            #pragma unroll
            for (int jr = 0; jr < 4; jr++)
                sOutB[(e + jr) * SOB_S + hh * SOB_H + col] = f2bf(acc[g][otl][jr] + ebv);
        }
    }
    if (wid == 0 && lc < 8) {
        float webv = web[lc];
        #pragma unroll
        for (int g = 0; g < 4; g++) {
            int e = 16 * g + lr4;
            #pragma unroll
            for (int jr = 0; jr < 4; jr++)
                sBias[(e + jr) * 12 + lc] = accb[g][jr] + webv;
        }
    }
    __syncthreads();

    // ---- per-edge epilogue (fp32 K/Q gathers; Q rows dst-sorted -> cached) --
    const int hp = t & 3;
    if (ge >= 0) {
        const float4* K4 = (const float4*)(Kh + (size_t)sIdx * 128);
        const float4* Q4 = (const float4*)(Qh + (size_t)dIdx * 128);
        const float inv_s4  = 0.5f;
        const float inv_s12 = 0.28867513459481288f;
        #pragma unroll
        for (int hi = 0; hi < 2; hi++) {
            int hh = 2 * hp + hi;
            float eb = sBias[e_l * 12 + hh];
            float4 kf[4], qf[4];
            #pragma unroll
            for (int j = 0; j < 4; j++) { kf[j] = K4[hh * 4 + j]; qf[j] = Q4[hh * 4 + j]; }
            float sem = kf[0].x*qf[0].x + kf[0].y*qf[0].y + kf[0].z*qf[0].z + kf[0].w*qf[0].w;
            float stl = 0.0f;
            #pragma unroll
            for (int j = 1; j < 4; j++)
                stl += kf[j].x*qf[j].x + kf[j].y*qf[j].y + kf[j].z*qf[j].z + kf[j].w*qf[j].w;
            float logit = sem * inv_s4 + stl * inv_s12 + eb;
            logit = fminf(fmaxf(logit, -CLAMP), CLAMP);
            float ex = __expf(logit);
            exS[(size_t)pos * 8 + hh] = ex;
            const ushort* srow = sOutB + e_l * SOB_S + hh * SOB_H;
            #pragma unroll
            for (int u = 0; u < 4; u++) {
                ushort4 ua = *(const ushort4*)(srow + 4 * u);
                ushort4 ub = *(const ushort4*)(srow + 16 + 4 * u);
                float4 A = make_float4(bf2f(ua.x), bf2f(ua.y), bf2f(ua.z), bf2f(ua.w));
                float4 B = make_float4(bf2f(ub.x), bf2f(ub.y), bf2f(ub.z), bf2f(ub.w));
                float4 kq = make_float4(kf[u].x + qf[u].x, kf[u].y + qf[u].y,
                                        kf[u].z + qf[u].z, kf[u].w + qf[u].w);
                float4 o;
                float v;
                v = kq.x * A.x; o.x = copysignf(sqrtf(fabsf(v)), v) + B.x;
                v = kq.y * A.y; o.y = copysignf(sqrtf(fabsf(v)), v) + B.y;
                v = kq.z * A.z; o.z = copysignf(sqrtf(fabsf(v)), v) + B.z;
                v = kq.w * A.w; o.w = copysignf(sqrtf(fabsf(v)), v) + B.w;
                *(float4*)(wE + (size_t)ge * 128 + hh * 16 + 4 * u) = o;
            }
        }
    }
}

// ---------------------------------------------------------------------------
// CSR build: count -> scan -> scatter (scatter also emits srcS/dstS)
// ---------------------------------------------------------------------------
__global__ __launch_bounds__(256) void count_kernel(
    const int* __restrict__ dstI, int* __restrict__ cnt)
{
    int e = blockIdx.x * 256 + threadIdx.x;
    if (e < NE) atomicAdd(&cnt[dstI[e]], 1);
}

__global__ __launch_bounds__(1024) void block_scan_kernel(
    const int* __restrict__ cnt, int* __restrict__ rowstart, int* __restrict__ bsum)
{
    __shared__ int sbuf[1024];
    const int b = blockIdx.x, t = threadIdx.x;
    const int i = b * 1024 + t;
    sbuf[t] = (i < N) ? cnt[i] : 0;
    __syncthreads();
    for (int off = 1; off < 1024; off <<= 1) {
        int xv = sbuf[t];
        int yv = (t >= off) ? sbuf[t - off] : 0;
        __syncthreads();
        sbuf[t] = xv + yv;
        __syncthreads();
    }
    if (i < N) rowstart[i + 1] = sbuf[t];
    if (t == 1023) bsum[b] = sbuf[1023];
}

__global__ void scan_totals_kernel(int* __restrict__ bsum, int nb)
{
    if (threadIdx.x == 0 && blockIdx.x == 0) {
        int run = 0;
        for (int b = 0; b < nb; b++) { int v = bsum[b]; bsum[b] = run; run += v; }
    }
}

__global__ __launch_bounds__(1024) void add_offsets_kernel(
    const int* __restrict__ bsum, int* __restrict__ rowstart)
{
    const int b = blockIdx.x, t = threadIdx.x;
    const int i = b * 1024 + t;
    if (i < N) rowstart[i + 1] += bsum[b];
    if (b == 0 && t == 0) rowstart[0] = 0;
}

__global__ __launch_bounds__(256) void scatter_kernel(
    const int* __restrict__ srcI, const int* __restrict__ dstI,
    const int* __restrict__ rowstart, int* __restrict__ cursor,
    int* __restrict__ elist, int* __restrict__ srcS, int* __restrict__ dstS)
{
    int e = blockIdx.x * 256 + threadIdx.x;
    if (e >= NE) return;
    int d = dstI[e];
    int pos = rowstart[d] + atomicAdd(&cursor[d], 1);
    elist[pos] = e;
    srcS[pos]  = srcI[e];
    dstS[pos]  = d;
}

// ---------------------------------------------------------------------------
// K3: gather-based wV — sequential exS/srcS reads, random bf16 Vh rows.
// ---------------------------------------------------------------------------
__global__ __launch_bounds__(256) void wv_kernel(
    const int* __restrict__ srcS, const int* __restrict__ rowstart,
    const ushort* __restrict__ Vh, const float* __restrict__ exS,
    float* __restrict__ wV)
{
    const int dd = blockIdx.x * 2 + (threadIdx.x >> 7);
    const int o  = threadIdx.x & 127;
    if (dd >= N) return;
    const int h  = o >> 4;
    const int st = rowstart[dd];
    const int en = rowstart[dd + 1];
    float den = 0.0f, num = 0.0f;
    int i = st;
    for (; i + 2 <= en; i += 2) {
        int s0 = srcS[i], s1 = srcS[i + 1];
        float ex0 = exS[(size_t)i * 8 + h];
        float ex1 = exS[(size_t)(i + 1) * 8 + h];
        float v0 = bf2f(Vh[(size_t)s0 * 128 + o]);
        float v1 = bf2f(Vh[(size_t)s1 * 128 + o]);
        num = fmaf(v0, ex0, num);
        num = fmaf(v1, ex1, num);
        den += ex0 + ex1;
    }
    if (i < en) {
        int s0 = srcS[i];
        float ex0 = exS[(size_t)i * 8 + h];
        num = fmaf(bf2f(Vh[(size_t)s0 * 128 + o]), ex0, num);
        den += ex0;
    }
    wV[(size_t)dd * 128 + o] = num / (den + 1e-16f);
}

// ---------------------------------------------------------------------------
extern "C" void kernel_launch(void* const* d_in, const int* in_sizes, int n_in,
                              void* d_out, int out_size, void* d_ws, size_t ws_size,
                              hipStream_t stream)
{
    const float* x         = (const float*)d_in[0];
    const int*   edge_idx  = (const int*)d_in[1];
    const float* rrwp      = (const float*)d_in[2];
    const float* edge_attr = (const float*)d_in[3];
    const float* Qw        = (const float*)d_in[4];
    const float* Qb        = (const float*)d_in[5];
    const float* Kw        = (const float*)d_in[6];
    const float* Kb        = (const float*)d_in[7];
    const float* Vw        = (const float*)d_in[8];
    const float* Vb        = (const float*)d_in[9];
    const float* Ew        = (const float*)d_in[10];
    const float* Eb        = (const float*)d_in[11];
    const float* wew       = (const float*)d_in[12];
    const float* web       = (const float*)d_in[13];
    const float* Wang      = (const float*)d_in[14];

    const int* srcI = edge_idx;
    const int* dstI = edge_idx + NE;

    float* wV = (float*)d_out;                       // N * 128
    float* wE = wV + (size_t)N * 128;                // NE * 128

    ushort* EwHiF = (ushort*)d_ws;                   // 34816 bf16
    ushort* EwLoF = EwHiF + 34816;                   // 34816
    ushort* QWHiF = EwLoF + 34816;                   // 49152
    ushort* QWLoF = QWHiF + 49152;                   // 49152
    ushort* VhB = QWLoF + 49152;                     // N*128 bf16
    float* Qh   = (float*)(VhB + (size_t)N * 128);   // N*128 fp32
    float* Kh   = Qh + (size_t)N * 128;
    float* exS  = Kh + (size_t)N * 128;              // NE*8 (position-indexed)
    int* cnt      = (int*)(exS + (size_t)NE * 8);    // N
    int* rowstart = cnt + N;                         // N+1
    int* cursor   = rowstart + (N + 1);              // N
    int* elist    = cursor + N;                      // NE
    int* srcS     = elist + NE;                      // NE
    int* dstS     = srcS + NE;                       // NE
    int* bsum     = dstS + NE;                       // 64

    const int NB_SCAN = (N + 1023) / 1024;           // 49

    hipMemsetAsync(cnt, 0, (size_t)N * sizeof(int), stream);
    hipMemsetAsync(cursor, 0, (size_t)N * sizeof(int), stream);

    prep_w_kernel<<<17, 256, 0, stream>>>(Ew, wew, EwHiF, EwLoF);
    prep_qkvw_kernel<<<24, 256, 0, stream>>>(Qw, Kw, Vw, QWHiF, QWLoF);

    qkv_mfma_kernel<<<(N + QNPB - 1) / QNPB, 256, 0, stream>>>(
        x, rrwp, QWHiF, QWLoF, Qb, Kb, Vb, Wang, Qh, Kh, VhB);

    count_kernel<<<(NE + 255) / 256, 256, 0, stream>>>(dstI, cnt);
    block_scan_kernel<<<NB_SCAN, 1024, 0, stream>>>(cnt, rowstart, bsum);
    scan_totals_kernel<<<1, 64, 0, stream>>>(bsum, NB_SCAN);
    add_offsets_kernel<<<NB_SCAN, 1024, 0, stream>>>(bsum, rowstart);
    scatter_kernel<<<(NE + 255) / 256, 256, 0, stream>>>(
        srcI, dstI, rowstart, cursor, elist, srcS, dstS);

    edge_gemm_kernel<<<(NE + 63) / 64, 256, 0, stream>>>(
        edge_attr, elist, srcS, dstS, Qh, Kh, EwHiF, EwLoF, Eb, web, wE, exS);

    wv_kernel<<<(N + 1) / 2, 256, 0, stream>>>(
        srcS, rowstart, VhB, exS, wV);
}

// Round 13
// 511.862 us; speedup vs baseline: 1.8870x; 1.2090x over previous
//
#include <hip/hip_runtime.h>
#include <hip/hip_bf16.h>
#include <math.h>

constexpr int N    = 50000;
constexpr int NE   = 500000;
constexpr int IN   = 128;
constexpr int H    = 8;
constexpr int D    = 16;
constexpr int DSEM = 4;
constexpr int KS   = 21;
constexpr float CLAMP = 5.0f;

typedef __attribute__((ext_vector_type(8))) __bf16 bf16x8;
typedef __attribute__((ext_vector_type(4))) float  f32x4;

__device__ inline f32x4 mfma16(bf16x8 a, bf16x8 b, f32x4 c) {
    return __builtin_amdgcn_mfma_f32_16x16x32_bf16(a, b, c, 0, 0, 0);
}

__device__ inline void split_bf16(float f, unsigned& hi, unsigned& lo) {
    unsigned u = __float_as_uint(f);
    hi = (u + 0x7FFFu + ((u >> 16) & 1u)) >> 16;
    float fl = f - __uint_as_float(hi << 16);
    unsigned ul = __float_as_uint(fl);
    lo = (ul + 0x7FFFu + ((ul >> 16) & 1u)) >> 16;
}

__device__ inline void split2(float a, float b, unsigned& hi, unsigned& lo) {
    unsigned ha, la, hb, lb;
    split_bf16(a, ha, la);
    split_bf16(b, hb, lb);
    hi = ha | (hb << 16);
    lo = la | (lb << 16);
}

__device__ inline ushort f2bf(float f) {
    unsigned u = __float_as_uint(f);
    return (ushort)((u + 0x7FFFu + ((u >> 16) & 1u)) >> 16);
}
__device__ inline float bf2f(ushort u) {
    return __uint_as_float(((unsigned)u) << 16);
}

// ---------------------------------------------------------------------------
// prep_w: split [Ew (256 rows); wew (8 rows); zeros (8 rows)] = 272x128 into
// bf16 hi/lo, fragment-linear.  17 o-tiles.
// ---------------------------------------------------------------------------
__global__ __launch_bounds__(256) void prep_w_kernel(
    const float* __restrict__ Ew, const float* __restrict__ wew,
    ushort* __restrict__ EwHiF, ushort* __restrict__ EwLoF)
{
    int tid = blockIdx.x * 256 + threadIdx.x;          // 0..4351
    int l  = tid & 63;
    int ks = (tid >> 6) & 3;
    int ot = tid >> 8;                                 // 0..16
    int row = 16 * ot + (l & 15);
    int col = 32 * ks + 8 * (l >> 4);
    float4 f0, f1;
    if (row < 256) {
        const float* src = Ew + (size_t)row * 128 + col;
        f0 = *(const float4*)(src);
        f1 = *(const float4*)(src + 4);
    } else if (row < 264) {
        const float* src = wew + (size_t)(row - 256) * 128 + col;
        f0 = *(const float4*)(src);
        f1 = *(const float4*)(src + 4);
    } else {
        f0 = f1 = make_float4(0.f, 0.f, 0.f, 0.f);
    }
    unsigned H0,L0,H1,L1,H2,L2,H3,L3;
    split2(f0.x, f0.y, H0, L0);
    split2(f0.z, f0.w, H1, L1);
    split2(f1.x, f1.y, H2, L2);
    split2(f1.z, f1.w, H3, L3);
    *(uint4*)(EwHiF + (size_t)tid * 8) = make_uint4(H0, H1, H2, H3);
    *(uint4*)(EwLoF + (size_t)tid * 8) = make_uint4(L0, L1, L2, L3);
}

// ---------------------------------------------------------------------------
// prep_qkvw: split concat(Qw,Kw,Vw) (384x128) into bf16 hi/lo, frag-linear.
// ---------------------------------------------------------------------------
__global__ __launch_bounds__(256) void prep_qkvw_kernel(
    const float* __restrict__ Qw, const float* __restrict__ Kw,
    const float* __restrict__ Vw,
    ushort* __restrict__ WHiF, ushort* __restrict__ WLoF)
{
    int tid = blockIdx.x * 256 + threadIdx.x;          // 0..6143
    int l  = tid & 63;
    int ks = (tid >> 6) & 3;
    int ot = tid >> 8;                                 // 0..23
    int row = 16 * ot + (l & 15);                      // 0..383
    int col = 32 * ks + 8 * (l >> 4);
    const float* wrow = (row < 128) ? (Qw + (size_t)row * 128)
                      : (row < 256) ? (Kw + (size_t)(row - 128) * 128)
                                    : (Vw + (size_t)(row - 256) * 128);
    const float* src = wrow + col;
    float4 f0 = *(const float4*)(src);
    float4 f1 = *(const float4*)(src + 4);
    unsigned H0,L0,H1,L1,H2,L2,H3,L3;
    split2(f0.x, f0.y, H0, L0);
    split2(f0.z, f0.w, H1, L1);
    split2(f1.x, f1.y, H2, L2);
    split2(f1.z, f1.w, H3, L3);
    *(uint4*)(WHiF + (size_t)tid * 8) = make_uint4(H0, H1, H2, H3);
    *(uint4*)(WLoF + (size_t)tid * 8) = make_uint4(L0, L1, L2, L3);
}

// ---------------------------------------------------------------------------
// K1: QKV split-bf16 MFMA + RoPE.  Qh/Kh fp32, Vh bf16. (unchanged)
// ---------------------------------------------------------------------------
constexpr int QNPB   = 32;
constexpr int QA_HI  = 0;
constexpr int QA_LO  = 8192;
constexpr int QSO_S  = 388;
constexpr int QSRR_OFF = 49664;
constexpr int QSC_OFF  = 52736;
constexpr int QSS_OFF  = 58880;
constexpr int Q_LDS    = 65024;

__global__ __launch_bounds__(256, 2) void qkv_mfma_kernel(
    const float* __restrict__ x, const float* __restrict__ rrwp,
    const ushort* __restrict__ WHiF, const ushort* __restrict__ WLoF,
    const float* __restrict__ Qb, const float* __restrict__ Kb,
    const float* __restrict__ Vb, const float* __restrict__ Wang,
    float* __restrict__ Qh, float* __restrict__ Kh, ushort* __restrict__ Vh)
{
    __shared__ __align__(16) char smem[Q_LDS];

    const int t    = threadIdx.x;
    const int wid  = t >> 6;
    const int lane = t & 63;
    const int nb0  = blockIdx.x * QNPB;

    float* srr = (float*)(smem + QSRR_OFF);
    float* scc = (float*)(smem + QSC_OFF);
    float* sss = (float*)(smem + QSS_OFF);

    for (int i = t; i < QNPB * KS; i += 256) {
        int nl = i / KS, k = i % KS;
        int n = nb0 + nl;
        srr[nl * 24 + k] = (n < N) ? rrwp[(size_t)n * KS + k] : 0.0f;
    }

    {
        const int se = t >> 3, sq = t & 7;
        const int sn = nb0 + se;
        const int g = se >> 4, sr = se & 15;
        const int cs2 = sq >> 1, lb = 2 * (sq & 1);
        const int abase = ((g * 4 + cs2) * 64 + lb * 16 + sr) * 16;
        float4 v0, v1, v2, v3;
        if (sn < N) {
            const float4* ar = (const float4*)(x + (size_t)sn * 128 + sq * 16);
            v0 = ar[0]; v1 = ar[1]; v2 = ar[2]; v3 = ar[3];
        } else {
            v0 = v1 = v2 = v3 = make_float4(0.f, 0.f, 0.f, 0.f);
        }
        unsigned H0,L0,H1,L1,H2,L2,H3,L3,H4,L4,H5,L5,H6,L6,H7,L7;
        split2(v0.x, v0.y, H0, L0); split2(v0.z, v0.w, H1, L1);
        split2(v1.x, v1.y, H2, L2); split2(v1.z, v1.w, H3, L3);
        split2(v2.x, v2.y, H4, L4); split2(v2.z, v2.w, H5, L5);
        split2(v3.x, v3.y, H6, L6); split2(v3.z, v3.w, H7, L7);
        *(uint4*)(smem + QA_HI + abase)       = make_uint4(H0, H1, H2, H3);
        *(uint4*)(smem + QA_HI + abase + 256) = make_uint4(H4, H5, H6, H7);
        *(uint4*)(smem + QA_LO + abase)       = make_uint4(L0, L1, L2, L3);
        *(uint4*)(smem + QA_LO + abase + 256) = make_uint4(L4, L5, L6, L7);
    }
    __syncthreads();

    f32x4 acc[2][6];
    #pragma unroll
    for (int g = 0; g < 2; g++)
        #pragma unroll
        for (int o = 0; o < 6; o++)
            acc[g][o] = (f32x4){0.f, 0.f, 0.f, 0.f};

    #pragma unroll
    for (int cs2 = 0; cs2 < 4; cs2++) {
        bf16x8 Ah[2], Al[2];
        #pragma unroll
        for (int g = 0; g < 2; g++) {
            int off = ((g * 4 + cs2) * 64 + lane) * 16;
            Ah[g] = *(const bf16x8*)(smem + QA_HI + off);
            Al[g] = *(const bf16x8*)(smem + QA_LO + off);
        }
        #pragma unroll
        for (int otl = 0; otl < 6; otl++) {
            int ot = wid * 6 + otl;
            size_t woff = (size_t)((ot * 4 + cs2) * 64 + lane) * 16;
            bf16x8 Bh = *(const bf16x8*)((const char*)WHiF + woff);
            bf16x8 Bl = *(const bf16x8*)((const char*)WLoF + woff);
            #pragma unroll
            for (int g = 0; g < 2; g++) {
                acc[g][otl] = mfma16(Ah[g], Bh, acc[g][otl]);
                acc[g][otl] = mfma16(Al[g], Bh, acc[g][otl]);
                acc[g][otl] = mfma16(Ah[g], Bl, acc[g][otl]);
            }
        }
    }
    __syncthreads();

    float* sout = (float*)smem;
    const int lr4 = (lane >> 4) * 4;
    const int lc  = lane & 15;
    #pragma unroll
    for (int otl = 0; otl < 6; otl++) {
        int o = (wid * 6 + otl) * 16 + lc;
        float bv = (o < 128) ? Qb[o] : (o < 256) ? Kb[o - 128] : Vb[o - 256];
        #pragma unroll
        for (int g = 0; g < 2; g++) {
            int e = 16 * g + lr4;
            #pragma unroll
            for (int jr = 0; jr < 4; jr++)
                sout[(e + jr) * QSO_S + o] = acc[g][otl][jr] + bv;
        }
    }
    __syncthreads();

    for (int i = t; i < QNPB * 48; i += 256) {
        int nl = i / 48, a = i % 48;
        int h = a / 6, r = a % 6;
        float av = 0.0f;
        #pragma unroll
        for (int k = 0; k < KS; k++)
            av = fmaf(srr[nl * 24 + k], Wang[(size_t)(h * KS + k) * 6 + r], av);
        float sv, cv;
        sincosf(av, &sv, &cv);
        scc[nl * 48 + a] = cv;
        sss[nl * 48 + a] = sv;
    }
    __syncthreads();

    for (int i = t; i < QNPB * 384; i += 256) {
        int nl = i / 384, o = i % 384;
        int n = nb0 + nl;
        if (n >= N) continue;
        int mat = o >> 7;
        int oo  = o & 127;
        int h = oo >> 4, d = oo & 15;
        float val;
        if (mat == 2 || d < DSEM) {
            val = sout[nl * QSO_S + o];
        } else {
            int i2 = (d - DSEM) >> 1;
            float cv = scc[nl * 48 + h * 6 + i2];
            float sv = sss[nl * 48 + h * 6 + i2];
            int base = (mat << 7) + h * 16 + DSEM + 2 * i2;
            float xe = sout[nl * QSO_S + base];
            float xo = sout[nl * QSO_S + base + 1];
            val = ((d & 1) == 0) ? (xe * cv - xo * sv) : (xe * sv + xo * cv);
        }
        if (mat == 2) {
            Vh[(size_t)n * 128 + oo] = f2bf(val);
        } else {
            float* dp = (mat == 0) ? Qh : Kh;
            dp[(size_t)n * 128 + oo] = val;
        }
    }
}

// ---------------------------------------------------------------------------
// K2 v6: 32 edges x 256 outs per block (grid = NE/32 exactly).
// Per-wave acc[2][4] = 32 AGPR (+8 bias on wave 0) -> fits 128-reg cap ->
// 4 waves/SIMD.  LDS 19.9 KB.  Staging thread = (edge, k-octet); epilogue
// thread = (edge, head).  dst-sorted edge order (elist/srcS/dstS).
// ---------------------------------------------------------------------------
constexpr int EPB     = 32;
constexpr int AHI_OFF = 0;        // [2 g][2 ks2][64 l][16 B] = 4096
constexpr int ALO_OFF = 4096;     // ends 8192
constexpr int SOB_S   = 288;      // ushorts per edge row (8 heads x 36)
constexpr int SOB_H   = 36;
constexpr int SBIAS_OFF = EPB * SOB_S * 2;            // 18432
constexpr int EDG_LDS   = SBIAS_OFF + EPB * 12 * 4;   // 19968

__global__ __launch_bounds__(256, 4) void edge_gemm_kernel(
    const float* __restrict__ edge_attr,
    const int* __restrict__ elist,
    const int* __restrict__ srcS, const int* __restrict__ dstS,
    const float* __restrict__ Qh, const float* __restrict__ Kh,
    const ushort* __restrict__ EwHiF, const ushort* __restrict__ EwLoF,
    const float* __restrict__ Eb, const float* __restrict__ web,
    float* __restrict__ wE, float* __restrict__ exS)
{
    __shared__ __align__(16) char smem[EDG_LDS];

    const int t    = threadIdx.x;
    const int wid  = t >> 6;
    const int lane = t & 63;
    const int eb0  = blockIdx.x * EPB;

    const int e_l = t >> 3;          // 0..31 (edge within block)
    const int j8  = t & 7;           // k-octet within 64-chunk / head in epilogue
    const int pos = eb0 + e_l;       // grid exact: always < NE
    const int ge   = elist[pos];
    const int sIdx = srcS[pos];
    const int dIdx = dstS[pos];

    const int sg    = e_l >> 4;      // 0..1
    const int sks2  = j8 >> 2;
    const int slane = (j8 & 3) * 16 + (e_l & 15);
    const int abase = ((sg * 2 + sks2) * 64 + slane) * 16;

    f32x4 acc[2][4];
    #pragma unroll
    for (int g = 0; g < 2; g++)
        #pragma unroll
        for (int o = 0; o < 4; o++)
            acc[g][o] = (f32x4){0.f, 0.f, 0.f, 0.f};
    f32x4 accb[2];
    #pragma unroll
    for (int g = 0; g < 2; g++) accb[g] = (f32x4){0.f, 0.f, 0.f, 0.f};

    #pragma unroll 1
    for (int c = 0; c < 2; c++) {
        // ---- stage A chunk c: one k-octet per thread ----
        {
            const float4* ar = (const float4*)(edge_attr + (size_t)ge * 128 + c * 64 + j8 * 8);
            float4 v0 = ar[0], v1 = ar[1];
            unsigned H0,L0,H1,L1,H2,L2,H3,L3;
            split2(v0.x, v0.y, H0, L0); split2(v0.z, v0.w, H1, L1);
            split2(v1.x, v1.y, H2, L2); split2(v1.z, v1.w, H3, L3);
            *(uint4*)(smem + AHI_OFF + abase) = make_uint4(H0, H1, H2, H3);
            *(uint4*)(smem + ALO_OFF + abase) = make_uint4(L0, L1, L2, L3);
        }
        __syncthreads();

        #pragma unroll
        for (int ks2 = 0; ks2 < 2; ks2++) {
            bf16x8 Wh[4], Wl[4];
            #pragma unroll
            for (int otl = 0; otl < 4; otl++) {
                int ot = wid * 4 + otl;
                size_t woff = (size_t)(((ot * 4 + c * 2 + ks2) * 64 + lane)) * 16;
                Wh[otl] = *(const bf16x8*)((const char*)EwHiF + woff);
                Wl[otl] = *(const bf16x8*)((const char*)EwLoF + woff);
            }
            bf16x8 Bbh, Bbl;
            if (wid == 0) {
                size_t woff = (size_t)(((16 * 4 + c * 2 + ks2) * 64 + lane)) * 16;
                Bbh = *(const bf16x8*)((const char*)EwHiF + woff);
                Bbl = *(const bf16x8*)((const char*)EwLoF + woff);
            }
            bf16x8 Ah[2], Al[2];
            #pragma unroll
            for (int g = 0; g < 2; g++) {
                int off = ((g * 2 + ks2) * 64 + lane) * 16;
                Ah[g] = *(const bf16x8*)(smem + AHI_OFF + off);
                Al[g] = *(const bf16x8*)(smem + ALO_OFF + off);
            }
            #pragma unroll
            for (int otl = 0; otl < 4; otl++) {
                #pragma unroll
                for (int g = 0; g < 2; g++) {
                    acc[g][otl] = mfma16(Ah[g], Wh[otl], acc[g][otl]);
                    acc[g][otl] = mfma16(Al[g], Wh[otl], acc[g][otl]);
                    acc[g][otl] = mfma16(Ah[g], Wl[otl], acc[g][otl]);
                }
            }
            if (wid == 0) {
                #pragma unroll
                for (int g = 0; g < 2; g++) {
                    accb[g] = mfma16(Ah[g], Bbh, accb[g]);
                    accb[g] = mfma16(Al[g], Bbh, accb[g]);
                    accb[g] = mfma16(Ah[g], Bbl, accb[g]);
                }
            }
        }
        __syncthreads();
    }

    // ---- acc -> bf16 sOut (+Eb), accb -> sBias (+web) ----
    ushort* sOutB = (ushort*)smem;
    float*  sBias = (float*)(smem + SBIAS_OFF);
    const int lr4 = (lane >> 4) * 4;
    const int lc  = lane & 15;
    #pragma unroll
    for (int otl = 0; otl < 4; otl++) {
        int o = (wid * 4 + otl) * 16 + lc;
        int hh = o >> 5, col = o & 31;
        float ebv = Eb[o];
        #pragma unroll
        for (int g = 0; g < 2; g++) {
            int e = 16 * g + lr4;
            #pragma unroll
            for (int jr = 0; jr < 4; jr++)
                sOutB[(e + jr) * SOB_S + hh * SOB_H + col] = f2bf(acc[g][otl][jr] + ebv);
        }
    }
    if (wid == 0 && lc < 8) {
        float webv = web[lc];
        #pragma unroll
        for (int g = 0; g < 2; g++) {
            int e = 16 * g + lr4;
            #pragma unroll
            for (int jr = 0; jr < 4; jr++)
                sBias[(e + jr) * 12 + lc] = accb[g][jr] + webv;
        }
    }
    __syncthreads();

    // ---- per-(edge,head) epilogue: thread = (e_l, hh=j8) ----
    {
        const int hh = j8;
        const float eb = sBias[e_l * 12 + hh];
        const float4* K4 = (const float4*)(Kh + (size_t)sIdx * 128);
        const float4* Q4 = (const float4*)(Qh + (size_t)dIdx * 128);
        const float inv_s4  = 0.5f;
        const float inv_s12 = 0.28867513459481288f;
        float4 kf[4], qf[4];
        #pragma unroll
        for (int j = 0; j < 4; j++) { kf[j] = K4[hh * 4 + j]; qf[j] = Q4[hh * 4 + j]; }
        float sem = kf[0].x*qf[0].x + kf[0].y*qf[0].y + kf[0].z*qf[0].z + kf[0].w*qf[0].w;
        float stl = 0.0f;
        #pragma unroll
        for (int j = 1; j < 4; j++)
            stl += kf[j].x*qf[j].x + kf[j].y*qf[j].y + kf[j].z*qf[j].z + kf[j].w*qf[j].w;
        float logit = sem * inv_s4 + stl * inv_s12 + eb;
        logit = fminf(fmaxf(logit, -CLAMP), CLAMP);
        float ex = __expf(logit);
        exS[(size_t)pos * 8 + hh] = ex;
        const ushort* srow = sOutB + e_l * SOB_S + hh * SOB_H;
        #pragma unroll
        for (int u = 0; u < 4; u++) {
            ushort4 ua = *(const ushort4*)(srow + 4 * u);
            ushort4 ub = *(const ushort4*)(srow + 16 + 4 * u);
            float4 A = make_float4(bf2f(ua.x), bf2f(ua.y), bf2f(ua.z), bf2f(ua.w));
            float4 B = make_float4(bf2f(ub.x), bf2f(ub.y), bf2f(ub.z), bf2f(ub.w));
            float4 kq = make_float4(kf[u].x + qf[u].x, kf[u].y + qf[u].y,
                                    kf[u].z + qf[u].z, kf[u].w + qf[u].w);
            float4 o;
            float v;
            v = kq.x * A.x; o.x = copysignf(sqrtf(fabsf(v)), v) + B.x;
            v = kq.y * A.y; o.y = copysignf(sqrtf(fabsf(v)), v) + B.y;
            v = kq.z * A.z; o.z = copysignf(sqrtf(fabsf(v)), v) + B.z;
            v = kq.w * A.w; o.w = copysignf(sqrtf(fabsf(v)), v) + B.w;
            *(float4*)(wE + (size_t)ge * 128 + hh * 16 + 4 * u) = o;
        }
    }
}

// ---------------------------------------------------------------------------
// CSR build: count -> scan -> scatter (scatter emits elist/srcS/dstS)
// ---------------------------------------------------------------------------
__global__ __launch_bounds__(256) void count_kernel(
    const int* __restrict__ dstI, int* __restrict__ cnt)
{
    int e = blockIdx.x * 256 + threadIdx.x;
    if (e < NE) atomicAdd(&cnt[dstI[e]], 1);
}

__global__ __launch_bounds__(1024) void block_scan_kernel(
    const int* __restrict__ cnt, int* __restrict__ rowstart, int* __restrict__ bsum)
{
    __shared__ int sbuf[1024];
    const int b = blockIdx.x, t = threadIdx.x;
    const int i = b * 1024 + t;
    sbuf[t] = (i < N) ? cnt[i] : 0;
    __syncthreads();
    for (int off = 1; off < 1024; off <<= 1) {
        int xv = sbuf[t];
        int yv = (t >= off) ? sbuf[t - off] : 0;
        __syncthreads();
        sbuf[t] = xv + yv;
        __syncthreads();
    }
    if (i < N) rowstart[i + 1] = sbuf[t];
    if (t == 1023) bsum[b] = sbuf[1023];
}

__global__ void scan_totals_kernel(int* __restrict__ bsum, int nb)
{
    if (threadIdx.x == 0 && blockIdx.x == 0) {
        int run = 0;
        for (int b = 0; b < nb; b++) { int v = bsum[b]; bsum[b] = run; run += v; }
    }
}

__global__ __launch_bounds__(1024) void add_offsets_kernel(
    const int* __restrict__ bsum, int* __restrict__ rowstart)
{
    const int b = blockIdx.x, t = threadIdx.x;
    const int i = b * 1024 + t;
    if (i < N) rowstart[i + 1] += bsum[b];
    if (b == 0 && t == 0) rowstart[0] = 0;
}

__global__ __launch_bounds__(256) void scatter_kernel(
    const int* __restrict__ srcI, const int* __restrict__ dstI,
    const int* __restrict__ rowstart, int* __restrict__ cursor,
    int* __restrict__ elist, int* __restrict__ srcS, int* __restrict__ dstS)
{
    int e = blockIdx.x * 256 + threadIdx.x;
    if (e >= NE) return;
    int d = dstI[e];
    int pos = rowstart[d] + atomicAdd(&cursor[d], 1);
    elist[pos] = e;
    srcS[pos]  = srcI[e];
    dstS[pos]  = d;
}

// ---------------------------------------------------------------------------
// K3: gather-based wV — sequential exS/srcS reads, random bf16 Vh rows.
// ---------------------------------------------------------------------------
__global__ __launch_bounds__(256) void wv_kernel(
    const int* __restrict__ srcS, const int* __restrict__ rowstart,
    const ushort* __restrict__ Vh, const float* __restrict__ exS,
    float* __restrict__ wV)
{
    const int dd = blockIdx.x * 2 + (threadIdx.x >> 7);
    const int o  = threadIdx.x & 127;
    if (dd >= N) return;
    const int h  = o >> 4;
    const int st = rowstart[dd];
    const int en = rowstart[dd + 1];
    float den = 0.0f, num = 0.0f;
    int i = st;
    for (; i + 2 <= en; i += 2) {
        int s0 = srcS[i], s1 = srcS[i + 1];
        float ex0 = exS[(size_t)i * 8 + h];
        float ex1 = exS[(size_t)(i + 1) * 8 + h];
        float v0 = bf2f(Vh[(size_t)s0 * 128 + o]);
        float v1 = bf2f(Vh[(size_t)s1 * 128 + o]);
        num = fmaf(v0, ex0, num);
        num = fmaf(v1, ex1, num);
        den += ex0 + ex1;
    }
    if (i < en) {
        int s0 = srcS[i];
        float ex0 = exS[(size_t)i * 8 + h];
        num = fmaf(bf2f(Vh[(size_t)s0 * 128 + o]), ex0, num);
        den += ex0;
    }
    wV[(size_t)dd * 128 + o] = num / (den + 1e-16f);
}

// ---------------------------------------------------------------------------
extern "C" void kernel_launch(void* const* d_in, const int* in_sizes, int n_in,
                              void* d_out, int out_size, void* d_ws, size_t ws_size,
                              hipStream_t stream)
{
    const float* x         = (const float*)d_in[0];
    const int*   edge_idx  = (const int*)d_in[1];
    const float* rrwp      = (const float*)d_in[2];
    const float* edge_attr = (const float*)d_in[3];
    const float* Qw        = (const float*)d_in[4];
    const float* Qb        = (const float*)d_in[5];
    const float* Kw        = (const float*)d_in[6];
    const float* Kb        = (const float*)d_in[7];
    const float* Vw        = (const float*)d_in[8];
    const float* Vb        = (const float*)d_in[9];
    const float* Ew        = (const float*)d_in[10];
    const float* Eb        = (const float*)d_in[11];
    const float* wew       = (const float*)d_in[12];
    const float* web       = (const float*)d_in[13];
    const float* Wang      = (const float*)d_in[14];

    const int* srcI = edge_idx;
    const int* dstI = edge_idx + NE;

    float* wV = (float*)d_out;                       // N * 128
    float* wE = wV + (size_t)N * 128;                // NE * 128

    ushort* EwHiF = (ushort*)d_ws;                   // 34816 bf16
    ushort* EwLoF = EwHiF + 34816;                   // 34816
    ushort* QWHiF = EwLoF + 34816;                   // 49152
    ushort* QWLoF = QWHiF + 49152;                   // 49152
    ushort* VhB = QWLoF + 49152;                     // N*128 bf16
    float* Qh   = (float*)(VhB + (size_t)N * 128);   // N*128 fp32
    float* Kh   = Qh + (size_t)N * 128;
    float* exS  = Kh + (size_t)N * 128;              // NE*8 (position-indexed)
    int* cnt      = (int*)(exS + (size_t)NE * 8);    // N
    int* rowstart = cnt + N;                         // N+1
    int* cursor   = rowstart + (N + 1);              // N
    int* elist    = cursor + N;                      // NE
    int* srcS     = elist + NE;                      // NE
    int* dstS     = srcS + NE;                       // NE
    int* bsum     = dstS + NE;                       // 64

    const int NB_SCAN = (N + 1023) / 1024;           // 49

    hipMemsetAsync(cnt, 0, (size_t)N * sizeof(int), stream);
    hipMemsetAsync(cursor, 0, (size_t)N * sizeof(int), stream);

    prep_w_kernel<<<17, 256, 0, stream>>>(Ew, wew, EwHiF, EwLoF);
    prep_qkvw_kernel<<<24, 256, 0, stream>>>(Qw, Kw, Vw, QWHiF, QWLoF);

    qkv_mfma_kernel<<<(N + QNPB - 1) / QNPB, 256, 0, stream>>>(
        x, rrwp, QWHiF, QWLoF, Qb, Kb, Vb, Wang, Qh, Kh, VhB);

    count_kernel<<<(NE + 255) / 256, 256, 0, stream>>>(dstI, cnt);
    block_scan_kernel<<<NB_SCAN, 1024, 0, stream>>>(cnt, rowstart, bsum);
    scan_totals_kernel<<<1, 64, 0, stream>>>(bsum, NB_SCAN);
    add_offsets_kernel<<<NB_SCAN, 1024, 0, stream>>>(bsum, rowstart);
    scatter_kernel<<<(NE + 255) / 256, 256, 0, stream>>>(
        srcI, dstI, rowstart, cursor, elist, srcS, dstS);

    edge_gemm_kernel<<<NE / EPB, 256, 0, stream>>>(
        edge_attr, elist, srcS, dstS, Qh, Kh, EwHiF, EwLoF, Eb, web, wE, exS);

    wv_kernel<<<(N + 1) / 2, 256, 0, stream>>>(
        srcS, rowstart, VhB, exS, wV);
}